// Round 8
// baseline (395.735 us; speedup 1.0000x reference)
//
#include <hip/hip_runtime.h>
#include <math.h>

#define N_NODES 8192
#define E_EDGES 262144
#define ETOT (E_EDGES + N_NODES)
#define F_IN 256
#define NH 4
#define NC 32
#define DD 128
#define NEG_SLOPE 0.2f
#define LN_EPS 1e-5f
// attention softmax in exp2 domain: fold log2(e)/sqrt(32) into Q at pack time
#define QK_SCALE (1.4426950408889634f / 5.656854249492381f)

typedef __attribute__((ext_vector_type(8))) short bf16x8;
typedef __attribute__((ext_vector_type(4))) float f32x4;

__device__ __forceinline__ float fexp2(float x) { return __builtin_amdgcn_exp2f(x); }
__device__ __forceinline__ float flog2(float x) { return __builtin_amdgcn_logf(x); }
__device__ __forceinline__ float frcp(float x)  { return __builtin_amdgcn_rcpf(x); }

__device__ __forceinline__ unsigned short f2bf(float f) {   // RTNE
    unsigned u = __float_as_uint(f);
    u += 0x7FFFu + ((u >> 16) & 1u);
    return (unsigned short)(u >> 16);
}
__device__ __forceinline__ unsigned pk2bf(float lo, float hi) {
    unsigned a = __float_as_uint(lo) + 0x8000u;
    unsigned b = __float_as_uint(hi) + 0x8000u;
    return __builtin_amdgcn_perm(b, a, 0x07060302u);
}

// ===== convert: x -> bf16 xb [N][256]; Wgat -> transposed bf16 Wgt [128][256] =====
__global__ __launch_bounds__(256) void k_cvt(const float* __restrict__ x,
                                             const float* __restrict__ Wgat,
                                             unsigned short* __restrict__ xb,
                                             unsigned short* __restrict__ Wgt) {
    int t = blockIdx.x * 256 + threadIdx.x;
    // xb: 2097152 elems, 4 per thread
    float4 v = *(const float4*)&x[(size_t)t * 4];
    ushort4 o;
    o.x = f2bf(v.x); o.y = f2bf(v.y); o.z = f2bf(v.z); o.w = f2bf(v.w);
    *(ushort4*)&xb[(size_t)t * 4] = o;
    // Wgt transpose: 32768 elems
    if (t < 128 * 256) {
        int c = t >> 8, k = t & 255;
        Wgt[t] = f2bf(Wgat[(size_t)k * 128 + c]);
    }
}

// ===== MFMA GEMM xw = x @ Wgat, fused attcoef epilogue =====
// block 256 (4 waves), 32 rows/block; wave w owns cols [w*32, w*32+32) = head w.
__global__ __launch_bounds__(256) void k_gemm_att(const unsigned short* __restrict__ xb,
                                                  const unsigned short* __restrict__ Wgt,
                                                  const float* __restrict__ att_src,
                                                  const float* __restrict__ att_dst,
                                                  float* __restrict__ xw,
                                                  float* __restrict__ asrc,
                                                  float* __restrict__ adst) {
    __shared__ unsigned short xs[32 * 256];   // chunk-rotated: row rr, chunk j at ((j+rr)&31)
    const int tid = threadIdx.x;
    const int w = tid >> 6, lane = tid & 63, lq = lane & 15, g = lane >> 4;
    const int n0 = blockIdx.x * 32;
    // stage x tile (32 rows x 256 k bf16), rotated chunks of 8 bf16
#pragma unroll
    for (int m = 0; m < 4; ++m) {
        int lin = m * 256 + tid;          // (row, chunk)
        int row = lin >> 5, ch = lin & 31;
        uint4 v = *(const uint4*)&xb[(size_t)(n0 + row) * 256 + ch * 8];
        *(uint4*)&xs[row * 256 + ((ch + row) & 31) * 8] = v;
    }
    __syncthreads();
    f32x4 zero = {0.f, 0.f, 0.f, 0.f};
    f32x4 acc[2][2];                       // [row-subtile s][c-tile cti]
#pragma unroll
    for (int s = 0; s < 2; ++s) { acc[s][0] = zero; acc[s][1] = zero; }
#pragma unroll
    for (int kb = 0; kb < 8; ++kb) {
        bf16x8 af[2], bf[2];
#pragma unroll
        for (int s = 0; s < 2; ++s) {
            int row = s * 16 + lq;
            af[s] = *(const bf16x8*)&xs[row * 256 + (((kb * 4 + g) + row) & 31) * 8];
        }
#pragma unroll
        for (int c = 0; c < 2; ++c)
            bf[c] = *(const bf16x8*)(Wgt + (size_t)(w * 32 + c * 16 + lq) * 256 + kb * 32 + g * 8);
#pragma unroll
        for (int s = 0; s < 2; ++s)
#pragma unroll
            for (int c = 0; c < 2; ++c)
                acc[s][c] = __builtin_amdgcn_mfma_f32_16x16x32_bf16(af[s], bf[c], acc[s][c], 0, 0, 0);
    }
    // store xw: lane holds rows s*16+4g+r, cols w*32+c*16+lq
#pragma unroll
    for (int s = 0; s < 2; ++s)
#pragma unroll
        for (int c = 0; c < 2; ++c)
#pragma unroll
            for (int r = 0; r < 4; ++r)
                xw[(size_t)(n0 + s * 16 + 4 * g + r) * DD + w * 32 + c * 16 + lq] = acc[s][c][r];
    // attcoef: per-row dot with att_src/att_dst over this wave's 32 cols (= head w)
    float avs0 = att_src[w * 32 + lq],      avd0 = att_dst[w * 32 + lq];
    float avs1 = att_src[w * 32 + 16 + lq], avd1 = att_dst[w * 32 + 16 + lq];
#pragma unroll
    for (int s = 0; s < 2; ++s) {
        f32x4 vs, vd;
#pragma unroll
        for (int r = 0; r < 4; ++r) {
            vs[r] = acc[s][0][r] * avs0 + acc[s][1][r] * avs1;
            vd[r] = acc[s][0][r] * avd0 + acc[s][1][r] * avd1;
        }
#pragma unroll
        for (int off = 1; off < 16; off <<= 1)
#pragma unroll
            for (int r = 0; r < 4; ++r) {
                vs[r] += __shfl_xor(vs[r], off);
                vd[r] += __shfl_xor(vd[r], off);
            }
        if (lq == 0) {
#pragma unroll
            for (int r = 0; r < 4; ++r) {
                asrc[(n0 + s * 16 + 4 * g + r) * 4 + w] = vs[r];
                adst[(n0 + s * 16 + 4 * g + r) * 4 + w] = vd[r];
            }
        }
    }
}

// ===== GEMM hbuf = hcat @ Wpro + Htb transpose + FUSED q/k projections =====
__global__ __launch_bounds__(128) void k_gemm_pro(const float* __restrict__ A,
                                                  const float* __restrict__ W,
                                                  const float* __restrict__ Wq,
                                                  const float* __restrict__ Wk,
                                                  float* __restrict__ out,
                                                  unsigned short* __restrict__ Htb,
                                                  unsigned short* __restrict__ Qb,
                                                  unsigned short* __restrict__ Kb) {
    __shared__ float as[16][DD];
    __shared__ float hs[16][DD];
    const int tid = threadIdx.x;
    const int r0 = blockIdx.x * 16;
    for (int idx = tid; idx < 16 * DD; idx += 128)
        as[idx >> 7][idx & 127] = A[(size_t)r0 * DD + idx];
    __syncthreads();
    float acc[16];
#pragma unroll
    for (int r = 0; r < 16; ++r) acc[r] = 0.f;
    for (int k = 0; k < DD; k += 4) {
        float w0 = W[(size_t)k * 128 + tid];
        float w1 = W[(size_t)(k + 1) * 128 + tid];
        float w2 = W[(size_t)(k + 2) * 128 + tid];
        float w3 = W[(size_t)(k + 3) * 128 + tid];
#pragma unroll
        for (int r = 0; r < 16; ++r) {
            float4 av = *(const float4*)&as[r][k];
            acc[r] += av.x * w0 + av.y * w1 + av.z * w2 + av.w * w3;
        }
    }
#pragma unroll
    for (int r = 0; r < 16; ++r) {
        out[(size_t)(r0 + r) * 128 + tid] = acc[r];
        hs[r][tid] = acc[r];
    }
    uint4 p0, p1;
    p0.x = (unsigned)f2bf(acc[0]) | ((unsigned)f2bf(acc[1]) << 16);
    p0.y = (unsigned)f2bf(acc[2]) | ((unsigned)f2bf(acc[3]) << 16);
    p0.z = (unsigned)f2bf(acc[4]) | ((unsigned)f2bf(acc[5]) << 16);
    p0.w = (unsigned)f2bf(acc[6]) | ((unsigned)f2bf(acc[7]) << 16);
    p1.x = (unsigned)f2bf(acc[8]) | ((unsigned)f2bf(acc[9]) << 16);
    p1.y = (unsigned)f2bf(acc[10]) | ((unsigned)f2bf(acc[11]) << 16);
    p1.z = (unsigned)f2bf(acc[12]) | ((unsigned)f2bf(acc[13]) << 16);
    p1.w = (unsigned)f2bf(acc[14]) | ((unsigned)f2bf(acc[15]) << 16);
    *(uint4*)(Htb + (size_t)tid * N_NODES + r0) = p0;
    *(uint4*)(Htb + (size_t)tid * N_NODES + r0 + 8) = p1;
    __syncthreads();
    const int head = tid >> 5, c = tid & 31;
    const float* wq = Wq + (size_t)head * DD * NC + c;
    const float* wk = Wk + (size_t)head * DD * NC + c;
    float q[16], kk[16];
#pragma unroll
    for (int n = 0; n < 16; ++n) { q[n] = 0.f; kk[n] = 0.f; }
    for (int d = 0; d < DD; d += 4) {
        float wq0 = wq[(size_t)d * NC],       wk0 = wk[(size_t)d * NC];
        float wq1 = wq[(size_t)(d + 1) * NC], wk1 = wk[(size_t)(d + 1) * NC];
        float wq2 = wq[(size_t)(d + 2) * NC], wk2 = wk[(size_t)(d + 2) * NC];
        float wq3 = wq[(size_t)(d + 3) * NC], wk3 = wk[(size_t)(d + 3) * NC];
#pragma unroll
        for (int n = 0; n < 16; ++n) {
            float4 hv = *(const float4*)&hs[n][d];
            q[n]  += hv.x * wq0 + hv.y * wq1 + hv.z * wq2 + hv.w * wq3;
            kk[n] += hv.x * wk0 + hv.y * wk1 + hv.z * wk2 + hv.w * wk3;
        }
    }
    unsigned short* qdst = Qb + ((size_t)head * N_NODES + r0) * NC + c;
    unsigned short* kdst = Kb + ((size_t)head * N_NODES + r0) * NC + c;
#pragma unroll
    for (int n = 0; n < 16; ++n) {
        qdst[n * NC] = f2bf(q[n] * QK_SCALE);
        kdst[n * NC] = f2bf(kk[n]);
    }
}

__device__ __forceinline__ void edge_sd(int e, const int* adj, int& s, int& d) {
    if (e < E_EDGES) { s = adj[e]; d = adj[E_EDGES + e]; }
    else { s = e - E_EDGES; d = s; }
}

// ===== edge pass: degree count + denom sum (exp recomputed later in fill) =====
__global__ void k_edge_pass1(const int* __restrict__ adj, const float* __restrict__ asrc,
                             const float* __restrict__ adst,
                             float* __restrict__ nodesum, int* __restrict__ deg) {
    int e = blockIdx.x * blockDim.x + threadIdx.x;
    if (e >= ETOT) return;
    int s, d; edge_sd(e, adj, s, d);
    atomicAdd(&deg[d], 1);
    float4 as4 = *(const float4*)&asrc[s * 4];
    float4 ad4 = *(const float4*)&adst[d * 4];
    const float L2E = 1.4426950408889634f;
    float v;
    float4 p;
    v = as4.x + ad4.x; v = v > 0.f ? v : NEG_SLOPE * v; p.x = fexp2(v * L2E);
    v = as4.y + ad4.y; v = v > 0.f ? v : NEG_SLOPE * v; p.y = fexp2(v * L2E);
    v = as4.z + ad4.z; v = v > 0.f ? v : NEG_SLOPE * v; p.z = fexp2(v * L2E);
    v = as4.w + ad4.w; v = v > 0.f ? v : NEG_SLOPE * v; p.w = fexp2(v * L2E);
    atomicAdd(&nodesum[d * 4 + 0], p.x);
    atomicAdd(&nodesum[d * 4 + 1], p.y);
    atomicAdd(&nodesum[d * 4 + 2], p.z);
    atomicAdd(&nodesum[d * 4 + 3], p.w);
}

// ===== single-block exclusive scan over deg[8192] -> rowptr, cursor =====
__global__ __launch_bounds__(1024) void k_scan(const int* __restrict__ deg,
                                               int* __restrict__ rowptr,
                                               int* __restrict__ cursor) {
    __shared__ int sm[1024];
    int t = threadIdx.x;
    int v[8], sum = 0;
#pragma unroll
    for (int j = 0; j < 8; ++j) { v[j] = deg[t * 8 + j]; sum += v[j]; }
    sm[t] = sum;
    __syncthreads();
    for (int off = 1; off < 1024; off <<= 1) {
        int x = (t >= off) ? sm[t - off] : 0;
        __syncthreads();
        sm[t] += x;
        __syncthreads();
    }
    int base = sm[t] - sum;
#pragma unroll
    for (int j = 0; j < 8; ++j) {
        rowptr[t * 8 + j] = base;
        cursor[t * 8 + j] = base;
        base += v[j];
    }
    if (t == 1023) rowptr[8192] = base;
}

// ===== fill CSR: recompute exp, pre-normalize alpha =====
__global__ void k_fill(const int* __restrict__ adj, const float* __restrict__ asrc,
                       const float* __restrict__ adst, const float* __restrict__ nodesum,
                       int* __restrict__ cursor,
                       int* __restrict__ src_csr, float* __restrict__ alpha_csr) {
    int e = blockIdx.x * blockDim.x + threadIdx.x;
    if (e >= ETOT) return;
    int s, d; edge_sd(e, adj, s, d);
    int pos = atomicAdd(&cursor[d], 1);
    float4 as4 = *(const float4*)&asrc[s * 4];
    float4 ad4 = *(const float4*)&adst[d * 4];
    float4 ns = *(const float4*)&nodesum[d * 4];
    const float L2E = 1.4426950408889634f;
    float v;
    float4 a;
    v = as4.x + ad4.x; v = v > 0.f ? v : NEG_SLOPE * v; a.x = fexp2(v * L2E) * frcp(ns.x);
    v = as4.y + ad4.y; v = v > 0.f ? v : NEG_SLOPE * v; a.y = fexp2(v * L2E) * frcp(ns.y);
    v = as4.z + ad4.z; v = v > 0.f ? v : NEG_SLOPE * v; a.z = fexp2(v * L2E) * frcp(ns.z);
    v = as4.w + ad4.w; v = v > 0.f ? v : NEG_SLOPE * v; a.w = fexp2(v * L2E) * frcp(ns.w);
    src_csr[pos] = s;
    *(float4*)&alpha_csr[(size_t)pos * 4] = a;
}

// ===== per-node gather-aggregate =====
__global__ __launch_bounds__(256) void k_aggregate(const int* __restrict__ rowptr,
                                                   const int* __restrict__ src_csr,
                                                   const float* __restrict__ alpha_csr,
                                                   const float* __restrict__ xw,
                                                   const float* __restrict__ bias,
                                                   float* __restrict__ hcat) {
    int n = blockIdx.x * 2 + (threadIdx.x >> 7);
    int c = threadIdx.x & 127;
    int h = c >> 5;
    int beg = rowptr[n], end = rowptr[n + 1];
    float acc = bias[c];
    int i = beg;
    for (; i + 2 <= end; i += 2) {
        int s0 = src_csr[i], s1 = src_csr[i + 1];
        float a0 = alpha_csr[(size_t)i * 4 + h];
        float a1 = alpha_csr[(size_t)(i + 1) * 4 + h];
        acc += a0 * xw[(size_t)s0 * DD + c] + a1 * xw[(size_t)s1 * DD + c];
    }
    if (i < end) {
        int s0 = src_csr[i];
        acc += alpha_csr[(size_t)i * 4 + h] * xw[(size_t)s0 * DD + c];
    }
    hcat[(size_t)n * DD + c] = acc;
}

// ===== attention pass A: l_h[n] = sum_m exp2(S) — 64q/block, ksplit 8 =====
__global__ __launch_bounds__(256) void k_attn_l(const unsigned short* __restrict__ Qb,
                                                const unsigned short* __restrict__ Kb,
                                                float* __restrict__ lsum) {
    const int tid = threadIdx.x;
    const int w = tid >> 6;
    const int lane = tid & 63;
    const int lq = lane & 15;
    const int g = lane >> 4;
    const int q0 = blockIdx.x * 64;
    const int ks = blockIdx.y;
    f32x4 zero = {0.f, 0.f, 0.f, 0.f};

    bf16x8 qf[4];
#pragma unroll
    for (int j = 0; j < 4; ++j)
        qf[j] = *(const bf16x8*)(Qb + ((size_t)w * N_NODES + q0 + j * 16 + lq) * NC + g * 8);
    const unsigned short* Kp = Kb + (size_t)w * N_NODES * NC;

    float l[4] = {0.f, 0.f, 0.f, 0.f};
    for (int kt = 0; kt < 16; ++kt) {
        const int k0 = ks * 1024 + kt * 64;
#pragma unroll
        for (int t = 0; t < 4; ++t) {
            const bf16x8 kf = *(const bf16x8*)(Kp + (size_t)(k0 + t * 16 + lq) * NC + g * 8);
#pragma unroll
            for (int j = 0; j < 4; ++j) {
                f32x4 st = __builtin_amdgcn_mfma_f32_16x16x32_bf16(kf, qf[j], zero, 0, 0, 0);
                l[j] += (fexp2(st[0]) + fexp2(st[1])) + (fexp2(st[2]) + fexp2(st[3]));
            }
        }
    }
#pragma unroll
    for (int j = 0; j < 4; ++j) {
        float lj = l[j];
        lj += __shfl_xor(lj, 16); lj += __shfl_xor(lj, 32);
        if (lane < 16) atomicAdd(&lsum[w * N_NODES + q0 + j * 16 + lq], lj);
    }
}

// ===== attention pass B: head-merged PV, 64q/block, ksplit 4 =====
__global__ __launch_bounds__(256, 2) void k_attn_pv(
        const unsigned short* __restrict__ Qb,
        const unsigned short* __restrict__ Kb,
        const unsigned short* __restrict__ Htb,
        const float* __restrict__ lsum,
        float* __restrict__ Opart) {
    __shared__ unsigned short htl[128 * 64];    // Ht tile, chunk-rotated (16 KB)
    __shared__ unsigned short plds[64][72];     // head-merged P (64q x 64k), padded rows
    const int tid = threadIdx.x;
    const int w = tid >> 6;
    const int lane = tid & 63;
    const int lq = lane & 15;
    const int g = lane >> 4;
    const int q0 = blockIdx.x * 64;
    const int ks = blockIdx.y;
    const int sd = tid >> 3, sc = tid & 7;
    f32x4 zero = {0.f, 0.f, 0.f, 0.f};

    float lg[4][4];           // [h][qsub]
    bf16x8 qreg[4][4];
#pragma unroll
    for (int h = 0; h < 4; ++h)
#pragma unroll
        for (int s = 0; s < 4; ++s) {
            lg[h][s] = -flog2(lsum[h * N_NODES + q0 + s * 16 + lq]);
            qreg[h][s] = *(const bf16x8*)(Qb + ((size_t)h * N_NODES + q0 + s * 16 + lq) * NC + g * 8);
        }

    f32x4 acc[2][4];          // [d-local][qsub]
#pragma unroll
    for (int a = 0; a < 2; ++a)
#pragma unroll
        for (int s = 0; s < 4; ++s) acc[a][s] = zero;

    for (int kt = 0; kt < 32; ++kt) {
        const int k0 = ks * 2048 + kt * 64;
        __syncthreads();   // htl/plds consumed by previous PV
#pragma unroll
        for (int mm = 0; mm < 4; ++mm) {
            int d = mm * 32 + sd;
            uint4 v = *(const uint4*)(Htb + (size_t)d * N_NODES + k0 + sc * 8);
            *(uint4*)&htl[d * 64 + ((sc + d) & 7) * 8] = v;
        }
        f32x4 ps[4] = {zero, zero, zero, zero};
#pragma unroll
        for (int h = 0; h < 4; ++h) {
            const bf16x8 kf = *(const bf16x8*)(Kb + ((size_t)h * N_NODES + k0 + w * 16 + lq) * NC + g * 8);
#pragma unroll
            for (int s = 0; s < 4; ++s) {
                f32x4 st = __builtin_amdgcn_mfma_f32_16x16x32_bf16(kf, qreg[h][s], zero, 0, 0, 0);
#pragma unroll
                for (int r = 0; r < 4; ++r)
                    ps[s][r] += fexp2(st[r] + lg[h][s]);
            }
        }
#pragma unroll
        for (int s = 0; s < 4; ++s) {
            uint2 pk;
            pk.x = pk2bf(ps[s][0], ps[s][1]);
            pk.y = pk2bf(ps[s][2], ps[s][3]);
            *(uint2*)&plds[s * 16 + lq][w * 16 + g * 4] = pk;
        }
        __syncthreads();   // htl + plds staged
#pragma unroll
        for (int kc = 0; kc < 2; ++kc) {
            bf16x8 af[4];
#pragma unroll
            for (int s = 0; s < 4; ++s)
                af[s] = *(const bf16x8*)&plds[s * 16 + lq][kc * 32 + g * 8];
#pragma unroll
            for (int dl = 0; dl < 2; ++dl) {
                int dd = (w * 2 + dl) * 16 + lq;
                const bf16x8 bf = *(const bf16x8*)&htl[dd * 64 + ((kc * 4 + g + dd) & 7) * 8];
#pragma unroll
                for (int s = 0; s < 4; ++s)
                    acc[dl][s] = __builtin_amdgcn_mfma_f32_16x16x32_bf16(af[s], bf, acc[dl][s], 0, 0, 0);
            }
        }
    }
    const size_t ob = (size_t)ks * N_NODES + q0;
#pragma unroll
    for (int dl = 0; dl < 2; ++dl) {
        int d = (w * 2 + dl) * 16 + lq;
#pragma unroll
        for (int s = 0; s < 4; ++s)
#pragma unroll
            for (int r = 0; r < 4; ++r)
                Opart[(ob + s * 16 + 4 * g + r) * DD + d] = acc[dl][s][r];
    }
}

// ===== combine splits, residual, LayerNorm =====
__global__ __launch_bounds__(128) void k_finalize(const float* __restrict__ Opart,
                                                  const float* __restrict__ hb,
                                                  const float* __restrict__ g,
                                                  const float* __restrict__ b,
                                                  float* __restrict__ out) {
    __shared__ float red[2];
    int n = blockIdx.x, c = threadIdx.x;
    const size_t ND = (size_t)N_NODES * DD;
    size_t idx = (size_t)n * DD + c;
    float y = Opart[idx] + Opart[ND + idx] + Opart[2 * ND + idx] + Opart[3 * ND + idx]
            + hb[idx];
    float s = y;
#pragma unroll
    for (int off = 1; off < 64; off <<= 1) s += __shfl_xor(s, off);
    if ((c & 63) == 0) red[c >> 6] = s;
    __syncthreads();
    float mu = (red[0] + red[1]) * (1.f / 128.f);
    float dv = y - mu;
    float vs = dv * dv;
#pragma unroll
    for (int off = 1; off < 64; off <<= 1) vs += __shfl_xor(vs, off);
    __syncthreads();
    if ((c & 63) == 0) red[c >> 6] = vs;
    __syncthreads();
    float rstd = rsqrtf((red[0] + red[1]) * (1.f / 128.f) + LN_EPS);
    out[idx] = dv * rstd * g[c] + b[c];
}

extern "C" void kernel_launch(void* const* d_in, const int* in_sizes, int n_in,
                              void* d_out, int out_size, void* d_ws, size_t ws_size,
                              hipStream_t stream) {
    const float* x        = (const float*)d_in[0];
    const int*   adj      = (const int*)d_in[1];
    const float* Wgat     = (const float*)d_in[2];
    const float* att_src  = (const float*)d_in[3];
    const float* att_dst  = (const float*)d_in[4];
    const float* bias_gat = (const float*)d_in[5];
    const float* Wq       = (const float*)d_in[6];
    const float* Wk       = (const float*)d_in[7];
    const float* Wpro     = (const float*)d_in[8];
    const float* ln_g     = (const float*)d_in[9];
    const float* ln_b     = (const float*)d_in[10];
    float* out = (float*)d_out;

    const size_t ND = (size_t)N_NODES * DD;
    unsigned short* Qb  = (unsigned short*)d_ws;          // 2 MB
    unsigned short* Kb  = Qb + (1 << 20);                 // 2 MB
    unsigned short* Htb = Kb + (1 << 20);                 // 2 MB
    unsigned short* xb  = Htb + (1 << 20);                // 4 MB  [N][256] bf16
    unsigned short* Wgt = xb + (size_t)N_NODES * F_IN;    // 64 KB [128][256] bf16
    float* xw      = (float*)(Wgt + 128 * 256);           // 4 MB
    float* hcat    = xw + ND;                             // 4 MB
    float* hbuf    = hcat + ND;                           // 4 MB
    float* asrc    = hbuf + ND;
    float* adst    = asrc + N_NODES * NH;
    float* nodesum = adst + N_NODES * NH;                 // memset w/ lsum
    float* lsum    = nodesum + N_NODES * NH;
    int*   deg     = (int*)(lsum + N_NODES * NH);
    int*   rowptr  = deg + 8192;
    int*   cursor  = rowptr + 8704;
    int*   src_csr = cursor + 8704;                       // ETOT ints
    float* alpha_csr = (float*)(src_csr + ETOT);          // ETOT*4 floats
    float* Opart   = alpha_csr + (size_t)ETOT * 4;        // 4 x [N,128] = 16 MB

    hipMemsetAsync(nodesum, 0, 2 * N_NODES * NH * sizeof(float), stream);
    hipMemsetAsync(deg, 0, N_NODES * sizeof(int), stream);
    k_cvt<<<(N_NODES * F_IN / 4 + 255) / 256, 256, 0, stream>>>(x, Wgat, xb, Wgt);
    k_gemm_att<<<N_NODES / 32, 256, 0, stream>>>(xb, Wgt, att_src, att_dst, xw, asrc, adst);
    int eblocks = (ETOT + 255) / 256;
    k_edge_pass1<<<eblocks, 256, 0, stream>>>(adj, asrc, adst, nodesum, deg);
    k_scan<<<1, 1024, 0, stream>>>(deg, rowptr, cursor);
    k_fill<<<eblocks, 256, 0, stream>>>(adj, asrc, adst, nodesum, cursor, src_csr, alpha_csr);
    k_aggregate<<<N_NODES / 2, 256, 0, stream>>>(rowptr, src_csr, alpha_csr, xw, bias_gat, hcat);
    k_gemm_pro<<<N_NODES / 16, 128, 0, stream>>>(hcat, Wpro, Wq, Wk, hbuf, Htb, Qb, Kb);
    dim3 lgrid(N_NODES / 64, 8);
    k_attn_l<<<lgrid, 256, 0, stream>>>(Qb, Kb, lsum);
    dim3 agrid(N_NODES / 64, 4);
    k_attn_pv<<<agrid, 256, 0, stream>>>(Qb, Kb, Htb, lsum, Opart);
    k_finalize<<<N_NODES, 128, 0, stream>>>(Opart, hbuf, ln_g, ln_b, out);
}

// Round 10
// 394.839 us; speedup vs baseline: 1.0023x; 1.0023x over previous
//
#include <hip/hip_runtime.h>
#include <math.h>

#define N_NODES 8192
#define E_EDGES 262144
#define ETOT (E_EDGES + N_NODES)
#define F_IN 256
#define NH 4
#define NC 32
#define DD 128
#define NEG_SLOPE 0.2f
#define LN_EPS 1e-5f
// attention softmax in exp2 domain: fold log2(e)/sqrt(32) into Q at pack time
#define QK_SCALE (1.4426950408889634f / 5.656854249492381f)

typedef __attribute__((ext_vector_type(8))) short bf16x8;
typedef __attribute__((ext_vector_type(4))) float f32x4;

__device__ __forceinline__ float fexp2(float x) { return __builtin_amdgcn_exp2f(x); }
__device__ __forceinline__ float flog2(float x) { return __builtin_amdgcn_logf(x); }
__device__ __forceinline__ float frcp(float x)  { return __builtin_amdgcn_rcpf(x); }

__device__ __forceinline__ unsigned short f2bf(float f) {   // RTNE
    unsigned u = __float_as_uint(f);
    u += 0x7FFFu + ((u >> 16) & 1u);
    return (unsigned short)(u >> 16);
}
__device__ __forceinline__ unsigned pk2bf(float lo, float hi) {
    unsigned a = __float_as_uint(lo) + 0x8000u;
    unsigned b = __float_as_uint(hi) + 0x8000u;
    return __builtin_amdgcn_perm(b, a, 0x07060302u);
}

// ===== tiny: Wgat -> transposed bf16 Wgt [128][256] =====
__global__ __launch_bounds__(256) void k_cvtw(const float* __restrict__ Wgat,
                                              unsigned short* __restrict__ Wgt) {
    int t = blockIdx.x * 256 + threadIdx.x;   // 32768 elems
    int c = t >> 8, k = t & 255;
    Wgt[t] = f2bf(Wgat[(size_t)k * 128 + c]);
}

// ===== MFMA GEMM xw = x @ Wgat, x converted to bf16 in staging, fused attcoef =====
// block 256 (4 waves), 32 rows/block; wave w owns cols [w*32, w*32+32) = head w.
__global__ __launch_bounds__(256) void k_gemm_att(const float* __restrict__ x,
                                                  const unsigned short* __restrict__ Wgt,
                                                  const float* __restrict__ att_src,
                                                  const float* __restrict__ att_dst,
                                                  float* __restrict__ xw,
                                                  float* __restrict__ asrc,
                                                  float* __restrict__ adst) {
    __shared__ unsigned short xs[32 * 256];   // chunk-rotated: row rr, chunk j at ((j+rr)&31)
    const int tid = threadIdx.x;
    const int w = tid >> 6, lane = tid & 63, lq = lane & 15, g = lane >> 4;
    const int n0 = blockIdx.x * 32;
    // stage x tile (32 rows x 32 chunks of 8), f32 -> bf16, rotated
#pragma unroll
    for (int m = 0; m < 4; ++m) {             // 4*256 = 1024 chunk-tasks
        int lin = m * 256 + tid;
        int row = lin >> 5, ch = lin & 31;
        const float* src = &x[(size_t)(n0 + row) * 256 + ch * 8];
        float4 v0 = *(const float4*)src;
        float4 v1 = *(const float4*)(src + 4);
        uint4 o;
        o.x = (unsigned)f2bf(v0.x) | ((unsigned)f2bf(v0.y) << 16);
        o.y = (unsigned)f2bf(v0.z) | ((unsigned)f2bf(v0.w) << 16);
        o.z = (unsigned)f2bf(v1.x) | ((unsigned)f2bf(v1.y) << 16);
        o.w = (unsigned)f2bf(v1.z) | ((unsigned)f2bf(v1.w) << 16);
        *(uint4*)&xs[row * 256 + ((ch + row) & 31) * 8] = o;
    }
    __syncthreads();
    f32x4 zero = {0.f, 0.f, 0.f, 0.f};
    f32x4 acc[2][2];                       // [row-subtile s][c-tile]
#pragma unroll
    for (int s = 0; s < 2; ++s) { acc[s][0] = zero; acc[s][1] = zero; }
#pragma unroll
    for (int kb = 0; kb < 8; ++kb) {
        bf16x8 af[2], bf[2];
#pragma unroll
        for (int s = 0; s < 2; ++s) {
            int row = s * 16 + lq;
            af[s] = *(const bf16x8*)&xs[row * 256 + (((kb * 4 + g) + row) & 31) * 8];
        }
#pragma unroll
        for (int c = 0; c < 2; ++c)
            bf[c] = *(const bf16x8*)(Wgt + (size_t)(w * 32 + c * 16 + lq) * 256 + kb * 32 + g * 8);
#pragma unroll
        for (int s = 0; s < 2; ++s)
#pragma unroll
            for (int c = 0; c < 2; ++c)
                acc[s][c] = __builtin_amdgcn_mfma_f32_16x16x32_bf16(af[s], bf[c], acc[s][c], 0, 0, 0);
    }
#pragma unroll
    for (int s = 0; s < 2; ++s)
#pragma unroll
        for (int c = 0; c < 2; ++c)
#pragma unroll
            for (int r = 0; r < 4; ++r)
                xw[(size_t)(n0 + s * 16 + 4 * g + r) * DD + w * 32 + c * 16 + lq] = acc[s][c][r];
    float avs0 = att_src[w * 32 + lq],      avd0 = att_dst[w * 32 + lq];
    float avs1 = att_src[w * 32 + 16 + lq], avd1 = att_dst[w * 32 + 16 + lq];
#pragma unroll
    for (int s = 0; s < 2; ++s) {
        f32x4 vs, vd;
#pragma unroll
        for (int r = 0; r < 4; ++r) {
            vs[r] = acc[s][0][r] * avs0 + acc[s][1][r] * avs1;
            vd[r] = acc[s][0][r] * avd0 + acc[s][1][r] * avd1;
        }
#pragma unroll
        for (int off = 1; off < 16; off <<= 1)
#pragma unroll
            for (int r = 0; r < 4; ++r) {
                vs[r] += __shfl_xor(vs[r], off);
                vd[r] += __shfl_xor(vd[r], off);
            }
        if (lq == 0) {
#pragma unroll
            for (int r = 0; r < 4; ++r) {
                asrc[(n0 + s * 16 + 4 * g + r) * 4 + w] = vs[r];
                adst[(n0 + s * 16 + 4 * g + r) * 4 + w] = vd[r];
            }
        }
    }
}

// ===== GEMM hbuf = hcat @ Wpro + Htb transpose + FUSED q/k projections =====
__global__ __launch_bounds__(128) void k_gemm_pro(const float* __restrict__ A,
                                                  const float* __restrict__ W,
                                                  const float* __restrict__ Wq,
                                                  const float* __restrict__ Wk,
                                                  float* __restrict__ out,
                                                  unsigned short* __restrict__ Htb,
                                                  unsigned short* __restrict__ Qb,
                                                  unsigned short* __restrict__ Kb) {
    __shared__ float as[16][DD];
    __shared__ float hs[16][DD];
    const int tid = threadIdx.x;
    const int r0 = blockIdx.x * 16;
    for (int idx = tid; idx < 16 * DD; idx += 128)
        as[idx >> 7][idx & 127] = A[(size_t)r0 * DD + idx];
    __syncthreads();
    float acc[16];
#pragma unroll
    for (int r = 0; r < 16; ++r) acc[r] = 0.f;
    for (int k = 0; k < DD; k += 4) {
        float w0 = W[(size_t)k * 128 + tid];
        float w1 = W[(size_t)(k + 1) * 128 + tid];
        float w2 = W[(size_t)(k + 2) * 128 + tid];
        float w3 = W[(size_t)(k + 3) * 128 + tid];
#pragma unroll
        for (int r = 0; r < 16; ++r) {
            float4 av = *(const float4*)&as[r][k];
            acc[r] += av.x * w0 + av.y * w1 + av.z * w2 + av.w * w3;
        }
    }
#pragma unroll
    for (int r = 0; r < 16; ++r) {
        out[(size_t)(r0 + r) * 128 + tid] = acc[r];
        hs[r][tid] = acc[r];
    }
    uint4 p0, p1;
    p0.x = (unsigned)f2bf(acc[0]) | ((unsigned)f2bf(acc[1]) << 16);
    p0.y = (unsigned)f2bf(acc[2]) | ((unsigned)f2bf(acc[3]) << 16);
    p0.z = (unsigned)f2bf(acc[4]) | ((unsigned)f2bf(acc[5]) << 16);
    p0.w = (unsigned)f2bf(acc[6]) | ((unsigned)f2bf(acc[7]) << 16);
    p1.x = (unsigned)f2bf(acc[8]) | ((unsigned)f2bf(acc[9]) << 16);
    p1.y = (unsigned)f2bf(acc[10]) | ((unsigned)f2bf(acc[11]) << 16);
    p1.z = (unsigned)f2bf(acc[12]) | ((unsigned)f2bf(acc[13]) << 16);
    p1.w = (unsigned)f2bf(acc[14]) | ((unsigned)f2bf(acc[15]) << 16);
    *(uint4*)(Htb + (size_t)tid * N_NODES + r0) = p0;
    *(uint4*)(Htb + (size_t)tid * N_NODES + r0 + 8) = p1;
    __syncthreads();
    const int head = tid >> 5, c = tid & 31;
    const float* wq = Wq + (size_t)head * DD * NC + c;
    const float* wk = Wk + (size_t)head * DD * NC + c;
    float q[16], kk[16];
#pragma unroll
    for (int n = 0; n < 16; ++n) { q[n] = 0.f; kk[n] = 0.f; }
    for (int d = 0; d < DD; d += 4) {
        float wq0 = wq[(size_t)d * NC],       wk0 = wk[(size_t)d * NC];
        float wq1 = wq[(size_t)(d + 1) * NC], wk1 = wk[(size_t)(d + 1) * NC];
        float wq2 = wq[(size_t)(d + 2) * NC], wk2 = wk[(size_t)(d + 2) * NC];
        float wq3 = wq[(size_t)(d + 3) * NC], wk3 = wk[(size_t)(d + 3) * NC];
#pragma unroll
        for (int n = 0; n < 16; ++n) {
            float4 hv = *(const float4*)&hs[n][d];
            q[n]  += hv.x * wq0 + hv.y * wq1 + hv.z * wq2 + hv.w * wq3;
            kk[n] += hv.x * wk0 + hv.y * wk1 + hv.z * wk2 + hv.w * wk3;
        }
    }
    unsigned short* qdst = Qb + ((size_t)head * N_NODES + r0) * NC + c;
    unsigned short* kdst = Kb + ((size_t)head * N_NODES + r0) * NC + c;
#pragma unroll
    for (int n = 0; n < 16; ++n) {
        qdst[n * NC] = f2bf(q[n] * QK_SCALE);
        kdst[n * NC] = f2bf(kk[n]);
    }
}

__device__ __forceinline__ void edge_sd(int e, const int* adj, int& s, int& d) {
    if (e < E_EDGES) { s = adj[e]; d = adj[E_EDGES + e]; }
    else { s = e - E_EDGES; d = s; }
}

// ===== edge pass: degree count + denom sum =====
__global__ void k_edge_pass1(const int* __restrict__ adj, const float* __restrict__ asrc,
                             const float* __restrict__ adst,
                             float* __restrict__ nodesum, int* __restrict__ deg) {
    int e = blockIdx.x * blockDim.x + threadIdx.x;
    if (e >= ETOT) return;
    int s, d; edge_sd(e, adj, s, d);
    atomicAdd(&deg[d], 1);
    float4 as4 = *(const float4*)&asrc[s * 4];
    float4 ad4 = *(const float4*)&adst[d * 4];
    const float L2E = 1.4426950408889634f;
    float v;
    float4 p;
    v = as4.x + ad4.x; v = v > 0.f ? v : NEG_SLOPE * v; p.x = fexp2(v * L2E);
    v = as4.y + ad4.y; v = v > 0.f ? v : NEG_SLOPE * v; p.y = fexp2(v * L2E);
    v = as4.z + ad4.z; v = v > 0.f ? v : NEG_SLOPE * v; p.z = fexp2(v * L2E);
    v = as4.w + ad4.w; v = v > 0.f ? v : NEG_SLOPE * v; p.w = fexp2(v * L2E);
    atomicAdd(&nodesum[d * 4 + 0], p.x);
    atomicAdd(&nodesum[d * 4 + 1], p.y);
    atomicAdd(&nodesum[d * 4 + 2], p.z);
    atomicAdd(&nodesum[d * 4 + 3], p.w);
}

// ===== single-block exclusive scan over deg[8192] -> rowptr, cursor =====
__global__ __launch_bounds__(1024) void k_scan(const int* __restrict__ deg,
                                               int* __restrict__ rowptr,
                                               int* __restrict__ cursor) {
    __shared__ int sm[1024];
    int t = threadIdx.x;
    int v[8], sum = 0;
#pragma unroll
    for (int j = 0; j < 8; ++j) { v[j] = deg[t * 8 + j]; sum += v[j]; }
    sm[t] = sum;
    __syncthreads();
    for (int off = 1; off < 1024; off <<= 1) {
        int x = (t >= off) ? sm[t - off] : 0;
        __syncthreads();
        sm[t] += x;
        __syncthreads();
    }
    int base = sm[t] - sum;
#pragma unroll
    for (int j = 0; j < 8; ++j) {
        rowptr[t * 8 + j] = base;
        cursor[t * 8 + j] = base;
        base += v[j];
    }
    if (t == 1023) rowptr[8192] = base;
}

// ===== fill CSR: recompute exp, pre-normalize alpha =====
__global__ void k_fill(const int* __restrict__ adj, const float* __restrict__ asrc,
                       const float* __restrict__ adst, const float* __restrict__ nodesum,
                       int* __restrict__ cursor,
                       int* __restrict__ src_csr, float* __restrict__ alpha_csr) {
    int e = blockIdx.x * blockDim.x + threadIdx.x;
    if (e >= ETOT) return;
    int s, d; edge_sd(e, adj, s, d);
    int pos = atomicAdd(&cursor[d], 1);
    float4 as4 = *(const float4*)&asrc[s * 4];
    float4 ad4 = *(const float4*)&adst[d * 4];
    float4 ns = *(const float4*)&nodesum[d * 4];
    const float L2E = 1.4426950408889634f;
    float v;
    float4 a;
    v = as4.x + ad4.x; v = v > 0.f ? v : NEG_SLOPE * v; a.x = fexp2(v * L2E) * frcp(ns.x);
    v = as4.y + ad4.y; v = v > 0.f ? v : NEG_SLOPE * v; a.y = fexp2(v * L2E) * frcp(ns.y);
    v = as4.z + ad4.z; v = v > 0.f ? v : NEG_SLOPE * v; a.z = fexp2(v * L2E) * frcp(ns.z);
    v = as4.w + ad4.w; v = v > 0.f ? v : NEG_SLOPE * v; a.w = fexp2(v * L2E) * frcp(ns.w);
    src_csr[pos] = s;
    *(float4*)&alpha_csr[(size_t)pos * 4] = a;
}

// ===== per-node gather-aggregate =====
__global__ __launch_bounds__(256) void k_aggregate(const int* __restrict__ rowptr,
                                                   const int* __restrict__ src_csr,
                                                   const float* __restrict__ alpha_csr,
                                                   const float* __restrict__ xw,
                                                   const float* __restrict__ bias,
                                                   float* __restrict__ hcat) {
    int n = blockIdx.x * 2 + (threadIdx.x >> 7);
    int c = threadIdx.x & 127;
    int h = c >> 5;
    int beg = rowptr[n], end = rowptr[n + 1];
    float acc = bias[c];
    int i = beg;
    for (; i + 2 <= end; i += 2) {
        int s0 = src_csr[i], s1 = src_csr[i + 1];
        float a0 = alpha_csr[(size_t)i * 4 + h];
        float a1 = alpha_csr[(size_t)(i + 1) * 4 + h];
        acc += a0 * xw[(size_t)s0 * DD + c] + a1 * xw[(size_t)s1 * DD + c];
    }
    if (i < end) {
        int s0 = src_csr[i];
        acc += alpha_csr[(size_t)i * 4 + h] * xw[(size_t)s0 * DD + c];
    }
    hcat[(size_t)n * DD + c] = acc;
}

// ===== attention pass A: l_h[n] = sum_m exp2(S) — 64q/block, ksplit 8 =====
__global__ __launch_bounds__(256) void k_attn_l(const unsigned short* __restrict__ Qb,
                                                const unsigned short* __restrict__ Kb,
                                                float* __restrict__ lsum) {
    const int tid = threadIdx.x;
    const int w = tid >> 6;
    const int lane = tid & 63;
    const int lq = lane & 15;
    const int g = lane >> 4;
    const int q0 = blockIdx.x * 64;
    const int ks = blockIdx.y;
    f32x4 zero = {0.f, 0.f, 0.f, 0.f};

    bf16x8 qf[4];
#pragma unroll
    for (int j = 0; j < 4; ++j)
        qf[j] = *(const bf16x8*)(Qb + ((size_t)w * N_NODES + q0 + j * 16 + lq) * NC + g * 8);
    const unsigned short* Kp = Kb + (size_t)w * N_NODES * NC;

    float l[4] = {0.f, 0.f, 0.f, 0.f};
    for (int kt = 0; kt < 16; ++kt) {
        const int k0 = ks * 1024 + kt * 64;
#pragma unroll
        for (int t = 0; t < 4; ++t) {
            const bf16x8 kf = *(const bf16x8*)(Kp + (size_t)(k0 + t * 16 + lq) * NC + g * 8);
#pragma unroll
            for (int j = 0; j < 4; ++j) {
                f32x4 st = __builtin_amdgcn_mfma_f32_16x16x32_bf16(kf, qf[j], zero, 0, 0, 0);
                l[j] += (fexp2(st[0]) + fexp2(st[1])) + (fexp2(st[2]) + fexp2(st[3]));
            }
        }
    }
#pragma unroll
    for (int j = 0; j < 4; ++j) {
        float lj = l[j];
        lj += __shfl_xor(lj, 16); lj += __shfl_xor(lj, 32);
        if (lane < 16) atomicAdd(&lsum[w * N_NODES + q0 + j * 16 + lq], lj);
    }
}

// ===== attention pass B: head-merged PV, 64q/block, ksplit 8 =====
__global__ __launch_bounds__(256, 2) void k_attn_pv(
        const unsigned short* __restrict__ Qb,
        const unsigned short* __restrict__ Kb,
        const unsigned short* __restrict__ Htb,
        const float* __restrict__ lsum,
        float* __restrict__ Opart) {
    __shared__ unsigned short htl[128 * 64];    // Ht tile, chunk-rotated (16 KB)
    __shared__ unsigned short plds[64][72];     // head-merged P (64q x 64k), padded rows
    const int tid = threadIdx.x;
    const int w = tid >> 6;
    const int lane = tid & 63;
    const int lq = lane & 15;
    const int g = lane >> 4;
    const int q0 = blockIdx.x * 64;
    const int ks = blockIdx.y;
    const int sd = tid >> 3, sc = tid & 7;
    f32x4 zero = {0.f, 0.f, 0.f, 0.f};

    float lg[4][4];           // [h][qsub]
    bf16x8 qreg[4][4];
#pragma unroll
    for (int h = 0; h < 4; ++h)
#pragma unroll
        for (int s = 0; s < 4; ++s) {
            lg[h][s] = -flog2(lsum[h * N_NODES + q0 + s * 16 + lq]);
            qreg[h][s] = *(const bf16x8*)(Qb + ((size_t)h * N_NODES + q0 + s * 16 + lq) * NC + g * 8);
        }

    f32x4 acc[2][4];          // [d-local][qsub]
#pragma unroll
    for (int a = 0; a < 2; ++a)
#pragma unroll
        for (int s = 0; s < 4; ++s) acc[a][s] = zero;

    for (int kt = 0; kt < 16; ++kt) {
        const int k0 = ks * 1024 + kt * 64;
        __syncthreads();   // htl/plds consumed by previous PV
#pragma unroll
        for (int mm = 0; mm < 4; ++mm) {
            int d = mm * 32 + sd;
            uint4 v = *(const uint4*)(Htb + (size_t)d * N_NODES + k0 + sc * 8);
            *(uint4*)&htl[d * 64 + ((sc + d) & 7) * 8] = v;
        }
        f32x4 ps[4] = {zero, zero, zero, zero};
#pragma unroll
        for (int h = 0; h < 4; ++h) {
            const bf16x8 kf = *(const bf16x8*)(Kb + ((size_t)h * N_NODES + k0 + w * 16 + lq) * NC + g * 8);
#pragma unroll
            for (int s = 0; s < 4; ++s) {
                f32x4 st = __builtin_amdgcn_mfma_f32_16x16x32_bf16(kf, qreg[h][s], zero, 0, 0, 0);
#pragma unroll
                for (int r = 0; r < 4; ++r)
                    ps[s][r] += fexp2(st[r] + lg[h][s]);
            }
        }
#pragma unroll
        for (int s = 0; s < 4; ++s) {
            uint2 pk;
            pk.x = pk2bf(ps[s][0], ps[s][1]);
            pk.y = pk2bf(ps[s][2], ps[s][3]);
            *(uint2*)&plds[s * 16 + lq][w * 16 + g * 4] = pk;
        }
        __syncthreads();   // htl + plds staged
#pragma unroll
        for (int kc = 0; kc < 2; ++kc) {
            bf16x8 af[4];
#pragma unroll
            for (int s = 0; s < 4; ++s)
                af[s] = *(const bf16x8*)&plds[s * 16 + lq][kc * 32 + g * 8];
#pragma unroll
            for (int dl = 0; dl < 2; ++dl) {
                int dd = (w * 2 + dl) * 16 + lq;
                const bf16x8 bf = *(const bf16x8*)&htl[dd * 64 + ((kc * 4 + g + dd) & 7) * 8];
#pragma unroll
                for (int s = 0; s < 4; ++s)
                    acc[dl][s] = __builtin_amdgcn_mfma_f32_16x16x32_bf16(af[s], bf, acc[dl][s], 0, 0, 0);
            }
        }
    }
    const size_t ob = (size_t)ks * N_NODES + q0;
#pragma unroll
    for (int dl = 0; dl < 2; ++dl) {
        int d = (w * 2 + dl) * 16 + lq;
#pragma unroll
        for (int s = 0; s < 4; ++s)
#pragma unroll
            for (int r = 0; r < 4; ++r)
                Opart[(ob + s * 16 + 4 * g + r) * DD + d] = acc[dl][s][r];
    }
}

// ===== combine 8 splits, residual, LayerNorm =====
__global__ __launch_bounds__(128) void k_finalize(const float* __restrict__ Opart,
                                                  const float* __restrict__ hb,
                                                  const float* __restrict__ g,
                                                  const float* __restrict__ b,
                                                  float* __restrict__ out) {
    __shared__ float red[2];
    int n = blockIdx.x, c = threadIdx.x;
    const size_t ND = (size_t)N_NODES * DD;
    size_t idx = (size_t)n * DD + c;
    float y = hb[idx];
#pragma unroll
    for (int i = 0; i < 8; ++i) y += Opart[i * ND + idx];
    float s = y;
#pragma unroll
    for (int off = 1; off < 64; off <<= 1) s += __shfl_xor(s, off);
    if ((c & 63) == 0) red[c >> 6] = s;
    __syncthreads();
    float mu = (red[0] + red[1]) * (1.f / 128.f);
    float dv = y - mu;
    float vs = dv * dv;
#pragma unroll
    for (int off = 1; off < 64; off <<= 1) vs += __shfl_xor(vs, off);
    __syncthreads();
    if ((c & 63) == 0) red[c >> 6] = vs;
    __syncthreads();
    float rstd = rsqrtf((red[0] + red[1]) * (1.f / 128.f) + LN_EPS);
    out[idx] = dv * rstd * g[c] + b[c];
}

extern "C" void kernel_launch(void* const* d_in, const int* in_sizes, int n_in,
                              void* d_out, int out_size, void* d_ws, size_t ws_size,
                              hipStream_t stream) {
    const float* x        = (const float*)d_in[0];
    const int*   adj      = (const int*)d_in[1];
    const float* Wgat     = (const float*)d_in[2];
    const float* att_src  = (const float*)d_in[3];
    const float* att_dst  = (const float*)d_in[4];
    const float* bias_gat = (const float*)d_in[5];
    const float* Wq       = (const float*)d_in[6];
    const float* Wk       = (const float*)d_in[7];
    const float* Wpro     = (const float*)d_in[8];
    const float* ln_g     = (const float*)d_in[9];
    const float* ln_b     = (const float*)d_in[10];
    float* out = (float*)d_out;

    const size_t ND = (size_t)N_NODES * DD;
    unsigned short* Qb  = (unsigned short*)d_ws;          // 2 MB
    unsigned short* Kb  = Qb + (1 << 20);                 // 2 MB
    unsigned short* Htb = Kb + (1 << 20);                 // 2 MB
    unsigned short* Wgt = Htb + (1 << 20);                // 64 KB [128][256] bf16
    float* xw      = (float*)(Wgt + 128 * 256);           // 4 MB
    float* hcat    = xw + ND;                             // 4 MB
    float* hbuf    = hcat + ND;                           // 4 MB
    float* asrc    = hbuf + ND;
    float* adst    = asrc + N_NODES * NH;
    float* nodesum = adst + N_NODES * NH;                 // memset w/ lsum
    float* lsum    = nodesum + N_NODES * NH;
    int*   deg     = (int*)(lsum + N_NODES * NH);
    int*   rowptr  = deg + 8192;
    int*   cursor  = rowptr + 8704;
    int*   src_csr = cursor + 8704;                       // ETOT ints
    float* alpha_csr = (float*)(src_csr + ETOT);          // ETOT*4 floats
    float* Opart   = alpha_csr + (size_t)ETOT * 4;        // 8 x [N,128] = 32 MB

    hipMemsetAsync(nodesum, 0, 2 * N_NODES * NH * sizeof(float), stream);
    hipMemsetAsync(deg, 0, N_NODES * sizeof(int), stream);
    k_cvtw<<<128, 256, 0, stream>>>(Wgat, Wgt);
    k_gemm_att<<<N_NODES / 32, 256, 0, stream>>>(x, Wgt, att_src, att_dst, xw, asrc, adst);
    int eblocks = (ETOT + 255) / 256;
    k_edge_pass1<<<eblocks, 256, 0, stream>>>(adj, asrc, adst, nodesum, deg);
    k_scan<<<1, 1024, 0, stream>>>(deg, rowptr, cursor);
    k_fill<<<eblocks, 256, 0, stream>>>(adj, asrc, adst, nodesum, cursor, src_csr, alpha_csr);
    k_aggregate<<<N_NODES / 2, 256, 0, stream>>>(rowptr, src_csr, alpha_csr, xw, bias_gat, hcat);
    k_gemm_pro<<<N_NODES / 16, 128, 0, stream>>>(hcat, Wpro, Wq, Wk, hbuf, Htb, Qb, Kb);
    dim3 lgrid(N_NODES / 64, 8);
    k_attn_l<<<lgrid, 256, 0, stream>>>(Qb, Kb, lsum);
    dim3 agrid(N_NODES / 64, 8);
    k_attn_pv<<<agrid, 256, 0, stream>>>(Qb, Kb, Htb, lsum, Opart);
    k_finalize<<<N_NODES, 128, 0, stream>>>(Opart, hbuf, ln_g, ln_b, out);
}

// Round 11
// 353.558 us; speedup vs baseline: 1.1193x; 1.1168x over previous
//
#include <hip/hip_runtime.h>
#include <math.h>

#define N_NODES 8192
#define E_EDGES 262144
#define ETOT (E_EDGES + N_NODES)
#define F_IN 256
#define NH 4
#define NC 32
#define DD 128
#define NEG_SLOPE 0.2f
#define LN_EPS 1e-5f
// attention softmax in exp2 domain: fold log2(e)/sqrt(32) into Q at pack time
#define QK_SCALE (1.4426950408889634f / 5.656854249492381f)

typedef __attribute__((ext_vector_type(8))) short bf16x8;
typedef __attribute__((ext_vector_type(4))) float f32x4;

__device__ __forceinline__ float fexp2(float x) { return __builtin_amdgcn_exp2f(x); }
__device__ __forceinline__ float flog2(float x) { return __builtin_amdgcn_logf(x); }
__device__ __forceinline__ float frcp(float x)  { return __builtin_amdgcn_rcpf(x); }

__device__ __forceinline__ unsigned short f2bf(float f) {   // RTNE
    unsigned u = __float_as_uint(f);
    u += 0x7FFFu + ((u >> 16) & 1u);
    return (unsigned short)(u >> 16);
}
__device__ __forceinline__ unsigned pk2bf(float lo, float hi) {
    unsigned a = __float_as_uint(lo) + 0x8000u;
    unsigned b = __float_as_uint(hi) + 0x8000u;
    return __builtin_amdgcn_perm(b, a, 0x07060302u);
}

// ===== tiny: Wgat -> transposed bf16 Wgt [128][256] =====
__global__ __launch_bounds__(256) void k_cvtw(const float* __restrict__ Wgat,
                                              unsigned short* __restrict__ Wgt) {
    int t = blockIdx.x * 256 + threadIdx.x;   // 32768 elems
    int c = t >> 8, k = t & 255;
    Wgt[t] = f2bf(Wgat[(size_t)k * 128 + c]);
}

// ===== MFMA GEMM xw = x @ Wgat, x converted to bf16 in staging, fused attcoef =====
__global__ __launch_bounds__(256) void k_gemm_att(const float* __restrict__ x,
                                                  const unsigned short* __restrict__ Wgt,
                                                  const float* __restrict__ att_src,
                                                  const float* __restrict__ att_dst,
                                                  float* __restrict__ xw,
                                                  float* __restrict__ asrc,
                                                  float* __restrict__ adst) {
    __shared__ unsigned short xs[32 * 256];   // chunk-rotated
    const int tid = threadIdx.x;
    const int w = tid >> 6, lane = tid & 63, lq = lane & 15, g = lane >> 4;
    const int n0 = blockIdx.x * 32;
#pragma unroll
    for (int m = 0; m < 4; ++m) {             // 1024 chunk-tasks
        int lin = m * 256 + tid;
        int row = lin >> 5, ch = lin & 31;
        const float* src = &x[(size_t)(n0 + row) * 256 + ch * 8];
        float4 v0 = *(const float4*)src;
        float4 v1 = *(const float4*)(src + 4);
        uint4 o;
        o.x = (unsigned)f2bf(v0.x) | ((unsigned)f2bf(v0.y) << 16);
        o.y = (unsigned)f2bf(v0.z) | ((unsigned)f2bf(v0.w) << 16);
        o.z = (unsigned)f2bf(v1.x) | ((unsigned)f2bf(v1.y) << 16);
        o.w = (unsigned)f2bf(v1.z) | ((unsigned)f2bf(v1.w) << 16);
        *(uint4*)&xs[row * 256 + ((ch + row) & 31) * 8] = o;
    }
    __syncthreads();
    f32x4 zero = {0.f, 0.f, 0.f, 0.f};
    f32x4 acc[2][2];
#pragma unroll
    for (int s = 0; s < 2; ++s) { acc[s][0] = zero; acc[s][1] = zero; }
#pragma unroll
    for (int kb = 0; kb < 8; ++kb) {
        bf16x8 af[2], bf[2];
#pragma unroll
        for (int s = 0; s < 2; ++s) {
            int row = s * 16 + lq;
            af[s] = *(const bf16x8*)&xs[row * 256 + (((kb * 4 + g) + row) & 31) * 8];
        }
#pragma unroll
        for (int c = 0; c < 2; ++c)
            bf[c] = *(const bf16x8*)(Wgt + (size_t)(w * 32 + c * 16 + lq) * 256 + kb * 32 + g * 8);
#pragma unroll
        for (int s = 0; s < 2; ++s)
#pragma unroll
            for (int c = 0; c < 2; ++c)
                acc[s][c] = __builtin_amdgcn_mfma_f32_16x16x32_bf16(af[s], bf[c], acc[s][c], 0, 0, 0);
    }
#pragma unroll
    for (int s = 0; s < 2; ++s)
#pragma unroll
        for (int c = 0; c < 2; ++c)
#pragma unroll
            for (int r = 0; r < 4; ++r)
                xw[(size_t)(n0 + s * 16 + 4 * g + r) * DD + w * 32 + c * 16 + lq] = acc[s][c][r];
    float avs0 = att_src[w * 32 + lq],      avd0 = att_dst[w * 32 + lq];
    float avs1 = att_src[w * 32 + 16 + lq], avd1 = att_dst[w * 32 + 16 + lq];
#pragma unroll
    for (int s = 0; s < 2; ++s) {
        f32x4 vs, vd;
#pragma unroll
        for (int r = 0; r < 4; ++r) {
            vs[r] = acc[s][0][r] * avs0 + acc[s][1][r] * avs1;
            vd[r] = acc[s][0][r] * avd0 + acc[s][1][r] * avd1;
        }
#pragma unroll
        for (int off = 1; off < 16; off <<= 1)
#pragma unroll
            for (int r = 0; r < 4; ++r) {
                vs[r] += __shfl_xor(vs[r], off);
                vd[r] += __shfl_xor(vd[r], off);
            }
        if (lq == 0) {
#pragma unroll
            for (int r = 0; r < 4; ++r) {
                asrc[(n0 + s * 16 + 4 * g + r) * 4 + w] = vs[r];
                adst[(n0 + s * 16 + 4 * g + r) * 4 + w] = vd[r];
            }
        }
    }
}

// ===== GEMM hbuf = hcat @ Wpro + Htb transpose + FUSED q/k projections =====
__global__ __launch_bounds__(128) void k_gemm_pro(const float* __restrict__ A,
                                                  const float* __restrict__ W,
                                                  const float* __restrict__ Wq,
                                                  const float* __restrict__ Wk,
                                                  float* __restrict__ out,
                                                  unsigned short* __restrict__ Htb,
                                                  unsigned short* __restrict__ Qb,
                                                  unsigned short* __restrict__ Kb) {
    __shared__ float as[16][DD];
    __shared__ float hs[16][DD];
    const int tid = threadIdx.x;
    const int r0 = blockIdx.x * 16;
    for (int idx = tid; idx < 16 * DD; idx += 128)
        as[idx >> 7][idx & 127] = A[(size_t)r0 * DD + idx];
    __syncthreads();
    float acc[16];
#pragma unroll
    for (int r = 0; r < 16; ++r) acc[r] = 0.f;
    for (int k = 0; k < DD; k += 4) {
        float w0 = W[(size_t)k * 128 + tid];
        float w1 = W[(size_t)(k + 1) * 128 + tid];
        float w2 = W[(size_t)(k + 2) * 128 + tid];
        float w3 = W[(size_t)(k + 3) * 128 + tid];
#pragma unroll
        for (int r = 0; r < 16; ++r) {
            float4 av = *(const float4*)&as[r][k];
            acc[r] += av.x * w0 + av.y * w1 + av.z * w2 + av.w * w3;
        }
    }
#pragma unroll
    for (int r = 0; r < 16; ++r) {
        out[(size_t)(r0 + r) * 128 + tid] = acc[r];
        hs[r][tid] = acc[r];
    }
    uint4 p0, p1;
    p0.x = (unsigned)f2bf(acc[0]) | ((unsigned)f2bf(acc[1]) << 16);
    p0.y = (unsigned)f2bf(acc[2]) | ((unsigned)f2bf(acc[3]) << 16);
    p0.z = (unsigned)f2bf(acc[4]) | ((unsigned)f2bf(acc[5]) << 16);
    p0.w = (unsigned)f2bf(acc[6]) | ((unsigned)f2bf(acc[7]) << 16);
    p1.x = (unsigned)f2bf(acc[8]) | ((unsigned)f2bf(acc[9]) << 16);
    p1.y = (unsigned)f2bf(acc[10]) | ((unsigned)f2bf(acc[11]) << 16);
    p1.z = (unsigned)f2bf(acc[12]) | ((unsigned)f2bf(acc[13]) << 16);
    p1.w = (unsigned)f2bf(acc[14]) | ((unsigned)f2bf(acc[15]) << 16);
    *(uint4*)(Htb + (size_t)tid * N_NODES + r0) = p0;
    *(uint4*)(Htb + (size_t)tid * N_NODES + r0 + 8) = p1;
    __syncthreads();
    const int head = tid >> 5, c = tid & 31;
    const float* wq = Wq + (size_t)head * DD * NC + c;
    const float* wk = Wk + (size_t)head * DD * NC + c;
    float q[16], kk[16];
#pragma unroll
    for (int n = 0; n < 16; ++n) { q[n] = 0.f; kk[n] = 0.f; }
    for (int d = 0; d < DD; d += 4) {
        float wq0 = wq[(size_t)d * NC],       wk0 = wk[(size_t)d * NC];
        float wq1 = wq[(size_t)(d + 1) * NC], wk1 = wk[(size_t)(d + 1) * NC];
        float wq2 = wq[(size_t)(d + 2) * NC], wk2 = wk[(size_t)(d + 2) * NC];
        float wq3 = wq[(size_t)(d + 3) * NC], wk3 = wk[(size_t)(d + 3) * NC];
#pragma unroll
        for (int n = 0; n < 16; ++n) {
            float4 hv = *(const float4*)&hs[n][d];
            q[n]  += hv.x * wq0 + hv.y * wq1 + hv.z * wq2 + hv.w * wq3;
            kk[n] += hv.x * wk0 + hv.y * wk1 + hv.z * wk2 + hv.w * wk3;
        }
    }
    unsigned short* qdst = Qb + ((size_t)head * N_NODES + r0) * NC + c;
    unsigned short* kdst = Kb + ((size_t)head * N_NODES + r0) * NC + c;
#pragma unroll
    for (int n = 0; n < 16; ++n) {
        qdst[n * NC] = f2bf(q[n] * QK_SCALE);
        kdst[n * NC] = f2bf(kk[n]);
    }
}

__device__ __forceinline__ void edge_sd(int e, const int* adj, int& s, int& d) {
    if (e < E_EDGES) { s = adj[e]; d = adj[E_EDGES + e]; }
    else { s = e - E_EDGES; d = s; }
}

// ===== edge pass: degree count + denom sum =====
__global__ void k_edge_pass1(const int* __restrict__ adj, const float* __restrict__ asrc,
                             const float* __restrict__ adst,
                             float* __restrict__ nodesum, int* __restrict__ deg) {
    int e = blockIdx.x * blockDim.x + threadIdx.x;
    if (e >= ETOT) return;
    int s, d; edge_sd(e, adj, s, d);
    atomicAdd(&deg[d], 1);
    float4 as4 = *(const float4*)&asrc[s * 4];
    float4 ad4 = *(const float4*)&adst[d * 4];
    const float L2E = 1.4426950408889634f;
    float v;
    float4 p;
    v = as4.x + ad4.x; v = v > 0.f ? v : NEG_SLOPE * v; p.x = fexp2(v * L2E);
    v = as4.y + ad4.y; v = v > 0.f ? v : NEG_SLOPE * v; p.y = fexp2(v * L2E);
    v = as4.z + ad4.z; v = v > 0.f ? v : NEG_SLOPE * v; p.z = fexp2(v * L2E);
    v = as4.w + ad4.w; v = v > 0.f ? v : NEG_SLOPE * v; p.w = fexp2(v * L2E);
    atomicAdd(&nodesum[d * 4 + 0], p.x);
    atomicAdd(&nodesum[d * 4 + 1], p.y);
    atomicAdd(&nodesum[d * 4 + 2], p.z);
    atomicAdd(&nodesum[d * 4 + 3], p.w);
}

// ===== single-block exclusive scan over deg[8192] -> rowptr, cursor =====
__global__ __launch_bounds__(1024) void k_scan(const int* __restrict__ deg,
                                               int* __restrict__ rowptr,
                                               int* __restrict__ cursor) {
    __shared__ int sm[1024];
    int t = threadIdx.x;
    int v[8], sum = 0;
#pragma unroll
    for (int j = 0; j < 8; ++j) { v[j] = deg[t * 8 + j]; sum += v[j]; }
    sm[t] = sum;
    __syncthreads();
    for (int off = 1; off < 1024; off <<= 1) {
        int x = (t >= off) ? sm[t - off] : 0;
        __syncthreads();
        sm[t] += x;
        __syncthreads();
    }
    int base = sm[t] - sum;
#pragma unroll
    for (int j = 0; j < 8; ++j) {
        rowptr[t * 8 + j] = base;
        cursor[t * 8 + j] = base;
        base += v[j];
    }
    if (t == 1023) rowptr[8192] = base;
}

// ===== fill CSR: recompute exp, pre-normalize alpha =====
__global__ void k_fill(const int* __restrict__ adj, const float* __restrict__ asrc,
                       const float* __restrict__ adst, const float* __restrict__ nodesum,
                       int* __restrict__ cursor,
                       int* __restrict__ src_csr, float* __restrict__ alpha_csr) {
    int e = blockIdx.x * blockDim.x + threadIdx.x;
    if (e >= ETOT) return;
    int s, d; edge_sd(e, adj, s, d);
    int pos = atomicAdd(&cursor[d], 1);
    float4 as4 = *(const float4*)&asrc[s * 4];
    float4 ad4 = *(const float4*)&adst[d * 4];
    float4 ns = *(const float4*)&nodesum[d * 4];
    const float L2E = 1.4426950408889634f;
    float v;
    float4 a;
    v = as4.x + ad4.x; v = v > 0.f ? v : NEG_SLOPE * v; a.x = fexp2(v * L2E) * frcp(ns.x);
    v = as4.y + ad4.y; v = v > 0.f ? v : NEG_SLOPE * v; a.y = fexp2(v * L2E) * frcp(ns.y);
    v = as4.z + ad4.z; v = v > 0.f ? v : NEG_SLOPE * v; a.z = fexp2(v * L2E) * frcp(ns.z);
    v = as4.w + ad4.w; v = v > 0.f ? v : NEG_SLOPE * v; a.w = fexp2(v * L2E) * frcp(ns.w);
    src_csr[pos] = s;
    *(float4*)&alpha_csr[(size_t)pos * 4] = a;
}

// ===== per-node gather-aggregate =====
__global__ __launch_bounds__(256) void k_aggregate(const int* __restrict__ rowptr,
                                                   const int* __restrict__ src_csr,
                                                   const float* __restrict__ alpha_csr,
                                                   const float* __restrict__ xw,
                                                   const float* __restrict__ bias,
                                                   float* __restrict__ hcat) {
    int n = blockIdx.x * 2 + (threadIdx.x >> 7);
    int c = threadIdx.x & 127;
    int h = c >> 5;
    int beg = rowptr[n], end = rowptr[n + 1];
    float acc = bias[c];
    int i = beg;
    for (; i + 2 <= end; i += 2) {
        int s0 = src_csr[i], s1 = src_csr[i + 1];
        float a0 = alpha_csr[(size_t)i * 4 + h];
        float a1 = alpha_csr[(size_t)(i + 1) * 4 + h];
        acc += a0 * xw[(size_t)s0 * DD + c] + a1 * xw[(size_t)s1 * DD + c];
    }
    if (i < end) {
        int s0 = src_csr[i];
        acc += alpha_csr[(size_t)i * 4 + h] * xw[(size_t)s0 * DD + c];
    }
    hcat[(size_t)n * DD + c] = acc;
}

// ===== attention pass A: l_h[n] = sum_m exp2(S) — 64q/block, ksplit 8 =====
__global__ __launch_bounds__(256) void k_attn_l(const unsigned short* __restrict__ Qb,
                                                const unsigned short* __restrict__ Kb,
                                                float* __restrict__ lsum) {
    const int tid = threadIdx.x;
    const int w = tid >> 6;
    const int lane = tid & 63;
    const int lq = lane & 15;
    const int g = lane >> 4;
    const int q0 = blockIdx.x * 64;
    const int ks = blockIdx.y;
    f32x4 zero = {0.f, 0.f, 0.f, 0.f};

    bf16x8 qf[4];
#pragma unroll
    for (int j = 0; j < 4; ++j)
        qf[j] = *(const bf16x8*)(Qb + ((size_t)w * N_NODES + q0 + j * 16 + lq) * NC + g * 8);
    const unsigned short* Kp = Kb + (size_t)w * N_NODES * NC;

    float l[4] = {0.f, 0.f, 0.f, 0.f};
    for (int kt = 0; kt < 16; ++kt) {
        const int k0 = ks * 1024 + kt * 64;
#pragma unroll
        for (int t = 0; t < 4; ++t) {
            const bf16x8 kf = *(const bf16x8*)(Kp + (size_t)(k0 + t * 16 + lq) * NC + g * 8);
#pragma unroll
            for (int j = 0; j < 4; ++j) {
                f32x4 st = __builtin_amdgcn_mfma_f32_16x16x32_bf16(kf, qf[j], zero, 0, 0, 0);
                l[j] += (fexp2(st[0]) + fexp2(st[1])) + (fexp2(st[2]) + fexp2(st[3]));
            }
        }
    }
#pragma unroll
    for (int j = 0; j < 4; ++j) {
        float lj = l[j];
        lj += __shfl_xor(lj, 16); lj += __shfl_xor(lj, 32);
        if (lane < 16) atomicAdd(&lsum[w * N_NODES + q0 + j * 16 + lq], lj);
    }
}

// ===== attention pass B: head-merged PV, 32q/block, ksplit 8, 20480B LDS =====
// plds is chunk-rotated (chunk 16B, rotated by +row) -> no pad, 8 blocks/CU.
__global__ __launch_bounds__(256, 2) void k_attn_pv(
        const unsigned short* __restrict__ Qb,
        const unsigned short* __restrict__ Kb,
        const unsigned short* __restrict__ Htb,
        const float* __restrict__ lsum,
        float* __restrict__ Opart) {
    __shared__ unsigned short htl[128 * 64];    // 16384 B, chunk-rotated
    __shared__ unsigned short plds[32 * 64];    // 4096 B, chunk-rotated
    const int tid = threadIdx.x;
    const int w = tid >> 6;
    const int lane = tid & 63;
    const int lq = lane & 15;
    const int g = lane >> 4;
    const int q0 = blockIdx.x * 32;
    const int ks = blockIdx.y;
    const int sd = tid >> 3, sc = tid & 7;
    f32x4 zero = {0.f, 0.f, 0.f, 0.f};

    float lg0[4], lg1[4];
    bf16x8 qreg0[4], qreg1[4];
#pragma unroll
    for (int h = 0; h < 4; ++h) {
        lg0[h] = -flog2(lsum[h * N_NODES + q0 + lq]);
        lg1[h] = -flog2(lsum[h * N_NODES + q0 + 16 + lq]);
        qreg0[h] = *(const bf16x8*)(Qb + ((size_t)h * N_NODES + q0 + lq) * NC + g * 8);
        qreg1[h] = *(const bf16x8*)(Qb + ((size_t)h * N_NODES + q0 + 16 + lq) * NC + g * 8);
    }

    f32x4 acc[2][2];   // [d-local][qsub]
#pragma unroll
    for (int a = 0; a < 2; ++a) { acc[a][0] = zero; acc[a][1] = zero; }

    // plds write slot: unswizzled chunk = 2w + (g>>1), half = g&1
    const int wch = 2 * w + (g >> 1);
    const int whalf = (g & 1) * 8;

    for (int kt = 0; kt < 16; ++kt) {
        const int k0 = ks * 1024 + kt * 64;
        __syncthreads();   // htl/plds consumed by previous PV
#pragma unroll
        for (int mm = 0; mm < 4; ++mm) {
            int d = mm * 32 + sd;
            uint4 v = *(const uint4*)(Htb + (size_t)d * N_NODES + k0 + sc * 8);
            *(uint4*)&htl[d * 64 + ((sc + d) & 7) * 8] = v;
        }
        f32x4 ps0 = zero, ps1 = zero;
#pragma unroll
        for (int h = 0; h < 4; ++h) {
            const bf16x8 kf = *(const bf16x8*)(Kb + ((size_t)h * N_NODES + k0 + w * 16 + lq) * NC + g * 8);
            f32x4 st0 = __builtin_amdgcn_mfma_f32_16x16x32_bf16(kf, qreg0[h], zero, 0, 0, 0);
            f32x4 st1 = __builtin_amdgcn_mfma_f32_16x16x32_bf16(kf, qreg1[h], zero, 0, 0, 0);
#pragma unroll
            for (int r = 0; r < 4; ++r) {
                ps0[r] += fexp2(st0[r] + lg0[h]);
                ps1[r] += fexp2(st1[r] + lg1[h]);
            }
        }
        uint2 pk;
        pk.x = pk2bf(ps0[0], ps0[1]); pk.y = pk2bf(ps0[2], ps0[3]);
        {
            int row = lq;
            *(uint2*)((char*)plds + row * 128 + ((wch + row) & 7) * 16 + whalf) = pk;
        }
        pk.x = pk2bf(ps1[0], ps1[1]); pk.y = pk2bf(ps1[2], ps1[3]);
        {
            int row = 16 + lq;
            *(uint2*)((char*)plds + row * 128 + ((wch + row) & 7) * 16 + whalf) = pk;
        }
        __syncthreads();   // htl + plds staged
#pragma unroll
        for (int kc = 0; kc < 2; ++kc) {
            int row0 = lq, row1 = 16 + lq;
            const bf16x8 af0 = *(const bf16x8*)((char*)plds + row0 * 128 + ((kc * 4 + g + row0) & 7) * 16);
            const bf16x8 af1 = *(const bf16x8*)((char*)plds + row1 * 128 + ((kc * 4 + g + row1) & 7) * 16);
#pragma unroll
            for (int dl = 0; dl < 2; ++dl) {
                int dd = (w * 2 + dl) * 16 + lq;
                const bf16x8 bf = *(const bf16x8*)&htl[dd * 64 + ((kc * 4 + g + dd) & 7) * 8];
                acc[dl][0] = __builtin_amdgcn_mfma_f32_16x16x32_bf16(af0, bf, acc[dl][0], 0, 0, 0);
                acc[dl][1] = __builtin_amdgcn_mfma_f32_16x16x32_bf16(af1, bf, acc[dl][1], 0, 0, 0);
            }
        }
    }
    const size_t ob = (size_t)ks * N_NODES + q0;
#pragma unroll
    for (int dl = 0; dl < 2; ++dl) {
        int d = (w * 2 + dl) * 16 + lq;
#pragma unroll
        for (int s = 0; s < 2; ++s)
#pragma unroll
            for (int r = 0; r < 4; ++r)
                Opart[(ob + s * 16 + 4 * g + r) * DD + d] = acc[dl][s][r];
    }
}

// ===== combine 8 splits, residual, LayerNorm =====
__global__ __launch_bounds__(128) void k_finalize(const float* __restrict__ Opart,
                                                  const float* __restrict__ hb,
                                                  const float* __restrict__ g,
                                                  const float* __restrict__ b,
                                                  float* __restrict__ out) {
    __shared__ float red[2];
    int n = blockIdx.x, c = threadIdx.x;
    const size_t ND = (size_t)N_NODES * DD;
    size_t idx = (size_t)n * DD + c;
    float y = hb[idx];
#pragma unroll
    for (int i = 0; i < 8; ++i) y += Opart[i * ND + idx];
    float s = y;
#pragma unroll
    for (int off = 1; off < 64; off <<= 1) s += __shfl_xor(s, off);
    if ((c & 63) == 0) red[c >> 6] = s;
    __syncthreads();
    float mu = (red[0] + red[1]) * (1.f / 128.f);
    float dv = y - mu;
    float vs = dv * dv;
#pragma unroll
    for (int off = 1; off < 64; off <<= 1) vs += __shfl_xor(vs, off);
    __syncthreads();
    if ((c & 63) == 0) red[c >> 6] = vs;
    __syncthreads();
    float rstd = rsqrtf((red[0] + red[1]) * (1.f / 128.f) + LN_EPS);
    out[idx] = dv * rstd * g[c] + b[c];
}

extern "C" void kernel_launch(void* const* d_in, const int* in_sizes, int n_in,
                              void* d_out, int out_size, void* d_ws, size_t ws_size,
                              hipStream_t stream) {
    const float* x        = (const float*)d_in[0];
    const int*   adj      = (const int*)d_in[1];
    const float* Wgat     = (const float*)d_in[2];
    const float* att_src  = (const float*)d_in[3];
    const float* att_dst  = (const float*)d_in[4];
    const float* bias_gat = (const float*)d_in[5];
    const float* Wq       = (const float*)d_in[6];
    const float* Wk       = (const float*)d_in[7];
    const float* Wpro     = (const float*)d_in[8];
    const float* ln_g     = (const float*)d_in[9];
    const float* ln_b     = (const float*)d_in[10];
    float* out = (float*)d_out;

    const size_t ND = (size_t)N_NODES * DD;
    unsigned short* Qb  = (unsigned short*)d_ws;          // 2 MB
    unsigned short* Kb  = Qb + (1 << 20);                 // 2 MB
    unsigned short* Htb = Kb + (1 << 20);                 // 2 MB
    unsigned short* Wgt = Htb + (1 << 20);                // 64 KB
    float* xw      = (float*)(Wgt + 128 * 256);           // 4 MB
    float* hcat    = xw + ND;                             // 4 MB
    float* hbuf    = hcat + ND;                           // 4 MB
    float* asrc    = hbuf + ND;
    float* adst    = asrc + N_NODES * NH;
    float* nodesum = adst + N_NODES * NH;                 // memset w/ lsum
    float* lsum    = nodesum + N_NODES * NH;
    int*   deg     = (int*)(lsum + N_NODES * NH);
    int*   rowptr  = deg + 8192;
    int*   cursor  = rowptr + 8704;
    int*   src_csr = cursor + 8704;                       // ETOT ints
    float* alpha_csr = (float*)(src_csr + ETOT);          // ETOT*4 floats
    float* Opart   = alpha_csr + (size_t)ETOT * 4;        // 8 x [N,128] = 32 MB

    hipMemsetAsync(nodesum, 0, 2 * N_NODES * NH * sizeof(float), stream);
    hipMemsetAsync(deg, 0, N_NODES * sizeof(int), stream);
    k_cvtw<<<128, 256, 0, stream>>>(Wgat, Wgt);
    k_gemm_att<<<N_NODES / 32, 256, 0, stream>>>(x, Wgt, att_src, att_dst, xw, asrc, adst);
    int eblocks = (ETOT + 255) / 256;
    k_edge_pass1<<<eblocks, 256, 0, stream>>>(adj, asrc, adst, nodesum, deg);
    k_scan<<<1, 1024, 0, stream>>>(deg, rowptr, cursor);
    k_fill<<<eblocks, 256, 0, stream>>>(adj, asrc, adst, nodesum, cursor, src_csr, alpha_csr);
    k_aggregate<<<N_NODES / 2, 256, 0, stream>>>(rowptr, src_csr, alpha_csr, xw, bias_gat, hcat);
    k_gemm_pro<<<N_NODES / 16, 128, 0, stream>>>(hcat, Wpro, Wq, Wk, hbuf, Htb, Qb, Kb);
    dim3 lgrid(N_NODES / 64, 8);
    k_attn_l<<<lgrid, 256, 0, stream>>>(Qb, Kb, lsum);
    dim3 agrid(N_NODES / 32, 8);
    k_attn_pv<<<agrid, 256, 0, stream>>>(Qb, Kb, Htb, lsum, Opart);
    k_finalize<<<N_NODES, 128, 0, stream>>>(Opart, hbuf, ln_g, ln_b, out);
}

// Round 12
// 319.325 us; speedup vs baseline: 1.2393x; 1.1072x over previous
//
#include <hip/hip_runtime.h>
#include <math.h>

#define N_NODES 8192
#define E_EDGES 262144
#define ETOT (E_EDGES + N_NODES)
#define F_IN 256
#define NH 4
#define NC 32
#define DD 128
#define NEG_SLOPE 0.2f
#define LN_EPS 1e-5f
// attention softmax in exp2 domain: fold log2(e)/sqrt(32) into Q at pack time
#define QK_SCALE (1.4426950408889634f / 5.656854249492381f)

typedef __attribute__((ext_vector_type(8))) short bf16x8;
typedef __attribute__((ext_vector_type(4))) float f32x4;

__device__ __forceinline__ float fexp2(float x) { return __builtin_amdgcn_exp2f(x); }
__device__ __forceinline__ float flog2(float x) { return __builtin_amdgcn_logf(x); }
__device__ __forceinline__ float frcp(float x)  { return __builtin_amdgcn_rcpf(x); }

__device__ __forceinline__ unsigned short f2bf(float f) {   // RTNE
    unsigned u = __float_as_uint(f);
    u += 0x7FFFu + ((u >> 16) & 1u);
    return (unsigned short)(u >> 16);
}
__device__ __forceinline__ unsigned pk2bf(float lo, float hi) {
    unsigned a = __float_as_uint(lo) + 0x8000u;
    unsigned b = __float_as_uint(hi) + 0x8000u;
    return __builtin_amdgcn_perm(b, a, 0x07060302u);
}

// ===== combined weight transpose/convert to bf16 =====
// Wgt[128 c][256 k] <- Wgat[k][c];  Wpt[128 c][128 k] <- Wpro[k][c];
// Wqt[4 h][32 c][128 k] <- Wq[h][k][c];  Wkt likewise.
__global__ __launch_bounds__(256) void k_cvt(const float* __restrict__ Wgat,
                                             const float* __restrict__ Wpro,
                                             const float* __restrict__ Wq,
                                             const float* __restrict__ Wk,
                                             unsigned short* __restrict__ Wgt,
                                             unsigned short* __restrict__ Wpt,
                                             unsigned short* __restrict__ Wqt,
                                             unsigned short* __restrict__ Wkt) {
    int t = blockIdx.x * 256 + threadIdx.x;   // 81920 total
    if (t < 32768) {
        int c = t >> 8, k = t & 255;
        Wgt[t] = f2bf(Wgat[(size_t)k * 128 + c]);
    } else if (t < 49152) {
        int i = t - 32768, c = i >> 7, k = i & 127;
        Wpt[i] = f2bf(Wpro[(size_t)k * 128 + c]);
    } else if (t < 65536) {
        int i = t - 49152, h = i >> 12, r = i & 4095, c = r >> 7, k = r & 127;
        Wqt[i] = f2bf(Wq[h * 4096 + k * 32 + c]);
    } else if (t < 81920) {
        int i = t - 65536, h = i >> 12, r = i & 4095, c = r >> 7, k = r & 127;
        Wkt[i] = f2bf(Wk[h * 4096 + k * 32 + c]);
    }
}

// ===== MFMA GEMM xw = x @ Wgat, x converted to bf16 in staging, fused attcoef =====
__global__ __launch_bounds__(256) void k_gemm_att(const float* __restrict__ x,
                                                  const unsigned short* __restrict__ Wgt,
                                                  const float* __restrict__ att_src,
                                                  const float* __restrict__ att_dst,
                                                  float* __restrict__ xw,
                                                  float* __restrict__ asrc,
                                                  float* __restrict__ adst) {
    __shared__ unsigned short xs[32 * 256];   // chunk-rotated
    const int tid = threadIdx.x;
    const int w = tid >> 6, lane = tid & 63, lq = lane & 15, g = lane >> 4;
    const int n0 = blockIdx.x * 32;
#pragma unroll
    for (int m = 0; m < 4; ++m) {             // 1024 chunk-tasks
        int lin = m * 256 + tid;
        int row = lin >> 5, ch = lin & 31;
        const float* src = &x[(size_t)(n0 + row) * 256 + ch * 8];
        float4 v0 = *(const float4*)src;
        float4 v1 = *(const float4*)(src + 4);
        uint4 o;
        o.x = (unsigned)f2bf(v0.x) | ((unsigned)f2bf(v0.y) << 16);
        o.y = (unsigned)f2bf(v0.z) | ((unsigned)f2bf(v0.w) << 16);
        o.z = (unsigned)f2bf(v1.x) | ((unsigned)f2bf(v1.y) << 16);
        o.w = (unsigned)f2bf(v1.z) | ((unsigned)f2bf(v1.w) << 16);
        *(uint4*)&xs[row * 256 + ((ch + row) & 31) * 8] = o;
    }
    __syncthreads();
    f32x4 zero = {0.f, 0.f, 0.f, 0.f};
    f32x4 acc[2][2];
#pragma unroll
    for (int s = 0; s < 2; ++s) { acc[s][0] = zero; acc[s][1] = zero; }
#pragma unroll
    for (int kb = 0; kb < 8; ++kb) {
        bf16x8 af[2], bf[2];
#pragma unroll
        for (int s = 0; s < 2; ++s) {
            int row = s * 16 + lq;
            af[s] = *(const bf16x8*)&xs[row * 256 + (((kb * 4 + g) + row) & 31) * 8];
        }
#pragma unroll
        for (int c = 0; c < 2; ++c)
            bf[c] = *(const bf16x8*)(Wgt + (size_t)(w * 32 + c * 16 + lq) * 256 + kb * 32 + g * 8);
#pragma unroll
        for (int s = 0; s < 2; ++s)
#pragma unroll
            for (int c = 0; c < 2; ++c)
                acc[s][c] = __builtin_amdgcn_mfma_f32_16x16x32_bf16(af[s], bf[c], acc[s][c], 0, 0, 0);
    }
#pragma unroll
    for (int s = 0; s < 2; ++s)
#pragma unroll
        for (int c = 0; c < 2; ++c)
#pragma unroll
            for (int r = 0; r < 4; ++r)
                xw[(size_t)(n0 + s * 16 + 4 * g + r) * DD + w * 32 + c * 16 + lq] = acc[s][c][r];
    float avs0 = att_src[w * 32 + lq],      avd0 = att_dst[w * 32 + lq];
    float avs1 = att_src[w * 32 + 16 + lq], avd1 = att_dst[w * 32 + 16 + lq];
#pragma unroll
    for (int s = 0; s < 2; ++s) {
        f32x4 vs, vd;
#pragma unroll
        for (int r = 0; r < 4; ++r) {
            vs[r] = acc[s][0][r] * avs0 + acc[s][1][r] * avs1;
            vd[r] = acc[s][0][r] * avd0 + acc[s][1][r] * avd1;
        }
#pragma unroll
        for (int off = 1; off < 16; off <<= 1)
#pragma unroll
            for (int r = 0; r < 4; ++r) {
                vs[r] += __shfl_xor(vs[r], off);
                vd[r] += __shfl_xor(vd[r], off);
            }
        if (lq == 0) {
#pragma unroll
            for (int r = 0; r < 4; ++r) {
                asrc[(n0 + s * 16 + 4 * g + r) * 4 + w] = vs[r];
                adst[(n0 + s * 16 + 4 * g + r) * 4 + w] = vd[r];
            }
        }
    }
}

// ===== MFMA GEMM h = hcat @ Wpro + hbuf f32 + Htb transpose + MFMA q/k =====
// block 256 (4 waves), 32 rows; wave w owns h-cols [w*32,w*32+32) and head w for q/k.
__global__ __launch_bounds__(256) void k_gemm_pro(const float* __restrict__ hcat,
                                                  const unsigned short* __restrict__ Wpt,
                                                  const unsigned short* __restrict__ Wqt,
                                                  const unsigned short* __restrict__ Wkt,
                                                  float* __restrict__ hbuf,
                                                  unsigned short* __restrict__ Htb,
                                                  unsigned short* __restrict__ Qb,
                                                  unsigned short* __restrict__ Kb) {
    __shared__ unsigned short xs[32 * 128];   // hcat bf16, chunk-rotated (16 chunks/row)
    __shared__ unsigned short hsd[32 * 128];  // h bf16 for q/k stage, chunk-rotated
    const int tid = threadIdx.x;
    const int w = tid >> 6, lane = tid & 63, lq = lane & 15, g = lane >> 4;
    const int n0 = blockIdx.x * 32;
    // stage hcat tile (32 rows x 16 chunks of 8), f32 -> bf16, rotated
#pragma unroll
    for (int m = 0; m < 2; ++m) {             // 512 chunk-tasks
        int lin = m * 256 + tid;
        int row = lin >> 4, ch = lin & 15;
        const float* src = &hcat[(size_t)(n0 + row) * 128 + ch * 8];
        float4 v0 = *(const float4*)src;
        float4 v1 = *(const float4*)(src + 4);
        uint4 o;
        o.x = (unsigned)f2bf(v0.x) | ((unsigned)f2bf(v0.y) << 16);
        o.y = (unsigned)f2bf(v0.z) | ((unsigned)f2bf(v0.w) << 16);
        o.z = (unsigned)f2bf(v1.x) | ((unsigned)f2bf(v1.y) << 16);
        o.w = (unsigned)f2bf(v1.z) | ((unsigned)f2bf(v1.w) << 16);
        *(uint4*)&xs[row * 128 + ((ch + row) & 15) * 8] = o;
    }
    __syncthreads();
    f32x4 zero = {0.f, 0.f, 0.f, 0.f};
    f32x4 acc[2][2];
#pragma unroll
    for (int s = 0; s < 2; ++s) { acc[s][0] = zero; acc[s][1] = zero; }
#pragma unroll
    for (int kb = 0; kb < 4; ++kb) {
        bf16x8 af[2], bf[2];
#pragma unroll
        for (int s = 0; s < 2; ++s) {
            int row = s * 16 + lq;
            af[s] = *(const bf16x8*)&xs[row * 128 + (((kb * 4 + g) + row) & 15) * 8];
        }
#pragma unroll
        for (int c = 0; c < 2; ++c)
            bf[c] = *(const bf16x8*)(Wpt + (size_t)(w * 32 + c * 16 + lq) * 128 + kb * 32 + g * 8);
#pragma unroll
        for (int s = 0; s < 2; ++s)
#pragma unroll
            for (int c = 0; c < 2; ++c)
                acc[s][c] = __builtin_amdgcn_mfma_f32_16x16x32_bf16(af[s], bf[c], acc[s][c], 0, 0, 0);
    }
    // epilogue A: hbuf f32, Htb transposed bf16, hsd LDS bf16 (rotated)
#pragma unroll
    for (int s = 0; s < 2; ++s)
#pragma unroll
        for (int c = 0; c < 2; ++c) {
            int col = w * 32 + c * 16 + lq;
#pragma unroll
            for (int r = 0; r < 4; ++r) {
                int row = s * 16 + 4 * g + r;
                hbuf[(size_t)(n0 + row) * 128 + col] = acc[s][c][r];
                hsd[row * 128 + (((col >> 3) + row) & 15) * 8 + (col & 7)] = f2bf(acc[s][c][r]);
            }
            uint2 hp;
            hp.x = pk2bf(acc[s][c][0], acc[s][c][1]);
            hp.y = pk2bf(acc[s][c][2], acc[s][c][3]);
            *(uint2*)(Htb + (size_t)col * N_NODES + n0 + s * 16 + 4 * g) = hp;
        }
    __syncthreads();
    // q/k projections for head w via MFMA (full d from hsd)
    f32x4 aq[2][2], ak[2][2];
#pragma unroll
    for (int s = 0; s < 2; ++s)
#pragma unroll
        for (int c = 0; c < 2; ++c) { aq[s][c] = zero; ak[s][c] = zero; }
#pragma unroll
    for (int kb = 0; kb < 4; ++kb) {
        bf16x8 af[2], bq[2], bk[2];
#pragma unroll
        for (int s = 0; s < 2; ++s) {
            int row = s * 16 + lq;
            af[s] = *(const bf16x8*)&hsd[row * 128 + (((kb * 4 + g) + row) & 15) * 8];
        }
#pragma unroll
        for (int c = 0; c < 2; ++c) {
            size_t widx = ((size_t)w * 32 + c * 16 + lq) * 128 + kb * 32 + g * 8;
            bq[c] = *(const bf16x8*)(Wqt + widx);
            bk[c] = *(const bf16x8*)(Wkt + widx);
        }
#pragma unroll
        for (int s = 0; s < 2; ++s)
#pragma unroll
            for (int c = 0; c < 2; ++c) {
                aq[s][c] = __builtin_amdgcn_mfma_f32_16x16x32_bf16(af[s], bq[c], aq[s][c], 0, 0, 0);
                ak[s][c] = __builtin_amdgcn_mfma_f32_16x16x32_bf16(af[s], bk[c], ak[s][c], 0, 0, 0);
            }
    }
    // q cols within head: c*16+lq (0..31); Qb[h][n][32]
#pragma unroll
    for (int s = 0; s < 2; ++s)
#pragma unroll
        for (int c = 0; c < 2; ++c)
#pragma unroll
            for (int r = 0; r < 4; ++r) {
                size_t nidx = (size_t)w * N_NODES + n0 + s * 16 + 4 * g + r;
                Qb[nidx * NC + c * 16 + lq] = f2bf(aq[s][c][r] * QK_SCALE);
                Kb[nidx * NC + c * 16 + lq] = f2bf(ak[s][c][r]);
            }
}

__device__ __forceinline__ void edge_sd(int e, const int* adj, int& s, int& d) {
    if (e < E_EDGES) { s = adj[e]; d = adj[E_EDGES + e]; }
    else { s = e - E_EDGES; d = s; }
}

// ===== degree count only =====
__global__ void k_deg(const int* __restrict__ adj, int* __restrict__ deg) {
    int e = blockIdx.x * blockDim.x + threadIdx.x;
    if (e >= ETOT) return;
    int d = (e < E_EDGES) ? adj[E_EDGES + e] : e - E_EDGES;
    atomicAdd(&deg[d], 1);
}

// ===== single-block exclusive scan over deg[8192] -> rowptr, cursor =====
__global__ __launch_bounds__(1024) void k_scan(const int* __restrict__ deg,
                                               int* __restrict__ rowptr,
                                               int* __restrict__ cursor) {
    __shared__ int sm[1024];
    int t = threadIdx.x;
    int v[8], sum = 0;
#pragma unroll
    for (int j = 0; j < 8; ++j) { v[j] = deg[t * 8 + j]; sum += v[j]; }
    sm[t] = sum;
    __syncthreads();
    for (int off = 1; off < 1024; off <<= 1) {
        int x = (t >= off) ? sm[t - off] : 0;
        __syncthreads();
        sm[t] += x;
        __syncthreads();
    }
    int base = sm[t] - sum;
#pragma unroll
    for (int j = 0; j < 8; ++j) {
        rowptr[t * 8 + j] = base;
        cursor[t * 8 + j] = base;
        base += v[j];
    }
    if (t == 1023) rowptr[8192] = base;
}

// ===== fill CSR: exp(leaky), raw p + src, nodesum atomics =====
__global__ void k_fill(const int* __restrict__ adj, const float* __restrict__ asrc,
                       const float* __restrict__ adst, int* __restrict__ cursor,
                       int* __restrict__ src_csr, float* __restrict__ p_csr,
                       float* __restrict__ nodesum) {
    int e = blockIdx.x * blockDim.x + threadIdx.x;
    if (e >= ETOT) return;
    int s, d; edge_sd(e, adj, s, d);
    int pos = atomicAdd(&cursor[d], 1);
    float4 as4 = *(const float4*)&asrc[s * 4];
    float4 ad4 = *(const float4*)&adst[d * 4];
    const float L2E = 1.4426950408889634f;
    float v;
    float4 p;
    v = as4.x + ad4.x; v = v > 0.f ? v : NEG_SLOPE * v; p.x = fexp2(v * L2E);
    v = as4.y + ad4.y; v = v > 0.f ? v : NEG_SLOPE * v; p.y = fexp2(v * L2E);
    v = as4.z + ad4.z; v = v > 0.f ? v : NEG_SLOPE * v; p.z = fexp2(v * L2E);
    v = as4.w + ad4.w; v = v > 0.f ? v : NEG_SLOPE * v; p.w = fexp2(v * L2E);
    src_csr[pos] = s;
    *(float4*)&p_csr[(size_t)pos * 4] = p;
    atomicAdd(&nodesum[d * 4 + 0], p.x);
    atomicAdd(&nodesum[d * 4 + 1], p.y);
    atomicAdd(&nodesum[d * 4 + 2], p.z);
    atomicAdd(&nodesum[d * 4 + 3], p.w);
}

// ===== per-node gather-aggregate (normalizes via rcp, 4-edge unroll) =====
__global__ __launch_bounds__(256) void k_aggregate(const int* __restrict__ rowptr,
                                                   const int* __restrict__ src_csr,
                                                   const float* __restrict__ p_csr,
                                                   const float* __restrict__ nodesum,
                                                   const float* __restrict__ xw,
                                                   const float* __restrict__ bias,
                                                   float* __restrict__ hcat) {
    int n = blockIdx.x * 2 + (threadIdx.x >> 7);
    int c = threadIdx.x & 127;
    int h = c >> 5;
    int beg = rowptr[n], end = rowptr[n + 1];
    float rden = frcp(nodesum[n * 4 + h]);
    float acc = bias[c];
    int i = beg;
    for (; i + 4 <= end; i += 4) {
        int s0 = src_csr[i], s1 = src_csr[i + 1], s2 = src_csr[i + 2], s3 = src_csr[i + 3];
        float a0 = p_csr[(size_t)i * 4 + h];
        float a1 = p_csr[(size_t)(i + 1) * 4 + h];
        float a2 = p_csr[(size_t)(i + 2) * 4 + h];
        float a3 = p_csr[(size_t)(i + 3) * 4 + h];
        acc += a0 * xw[(size_t)s0 * DD + c] + a1 * xw[(size_t)s1 * DD + c]
             + a2 * xw[(size_t)s2 * DD + c] + a3 * xw[(size_t)s3 * DD + c];
    }
    for (; i < end; ++i) {
        int s0 = src_csr[i];
        acc += p_csr[(size_t)i * 4 + h] * xw[(size_t)s0 * DD + c];
    }
    float norm = acc - bias[c];
    hcat[(size_t)n * DD + c] = bias[c] + norm * rden;
}

// ===== attention pass A: l_h[n] = sum_m exp2(S) — 64q/block, ksplit 8 =====
__global__ __launch_bounds__(256) void k_attn_l(const unsigned short* __restrict__ Qb,
                                                const unsigned short* __restrict__ Kb,
                                                float* __restrict__ lsum) {
    const int tid = threadIdx.x;
    const int w = tid >> 6;
    const int lane = tid & 63;
    const int lq = lane & 15;
    const int g = lane >> 4;
    const int q0 = blockIdx.x * 64;
    const int ks = blockIdx.y;
    f32x4 zero = {0.f, 0.f, 0.f, 0.f};

    bf16x8 qf[4];
#pragma unroll
    for (int j = 0; j < 4; ++j)
        qf[j] = *(const bf16x8*)(Qb + ((size_t)w * N_NODES + q0 + j * 16 + lq) * NC + g * 8);
    const unsigned short* Kp = Kb + (size_t)w * N_NODES * NC;

    float l[4] = {0.f, 0.f, 0.f, 0.f};
    for (int kt = 0; kt < 16; ++kt) {
        const int k0 = ks * 1024 + kt * 64;
#pragma unroll
        for (int t = 0; t < 4; ++t) {
            const bf16x8 kf = *(const bf16x8*)(Kp + (size_t)(k0 + t * 16 + lq) * NC + g * 8);
#pragma unroll
            for (int j = 0; j < 4; ++j) {
                f32x4 st = __builtin_amdgcn_mfma_f32_16x16x32_bf16(kf, qf[j], zero, 0, 0, 0);
                l[j] += (fexp2(st[0]) + fexp2(st[1])) + (fexp2(st[2]) + fexp2(st[3]));
            }
        }
    }
#pragma unroll
    for (int j = 0; j < 4; ++j) {
        float lj = l[j];
        lj += __shfl_xor(lj, 16); lj += __shfl_xor(lj, 32);
        if (lane < 16) atomicAdd(&lsum[w * N_NODES + q0 + j * 16 + lq], lj);
    }
}

// ===== attention pass B: head-merged PV, 32q/block, ksplit 8, 20480B LDS =====
__global__ __launch_bounds__(256, 2) void k_attn_pv(
        const unsigned short* __restrict__ Qb,
        const unsigned short* __restrict__ Kb,
        const unsigned short* __restrict__ Htb,
        const float* __restrict__ lsum,
        float* __restrict__ Opart) {
    __shared__ unsigned short htl[128 * 64];    // 16384 B, chunk-rotated
    __shared__ unsigned short plds[32 * 64];    // 4096 B, chunk-rotated
    const int tid = threadIdx.x;
    const int w = tid >> 6;
    const int lane = tid & 63;
    const int lq = lane & 15;
    const int g = lane >> 4;
    const int q0 = blockIdx.x * 32;
    const int ks = blockIdx.y;
    const int sd = tid >> 3, sc = tid & 7;
    f32x4 zero = {0.f, 0.f, 0.f, 0.f};

    float lg0[4], lg1[4];
    bf16x8 qreg0[4], qreg1[4];
#pragma unroll
    for (int h = 0; h < 4; ++h) {
        lg0[h] = -flog2(lsum[h * N_NODES + q0 + lq]);
        lg1[h] = -flog2(lsum[h * N_NODES + q0 + 16 + lq]);
        qreg0[h] = *(const bf16x8*)(Qb + ((size_t)h * N_NODES + q0 + lq) * NC + g * 8);
        qreg1[h] = *(const bf16x8*)(Qb + ((size_t)h * N_NODES + q0 + 16 + lq) * NC + g * 8);
    }

    f32x4 acc[2][2];
#pragma unroll
    for (int a = 0; a < 2; ++a) { acc[a][0] = zero; acc[a][1] = zero; }

    const int wch = 2 * w + (g >> 1);
    const int whalf = (g & 1) * 8;

    for (int kt = 0; kt < 16; ++kt) {
        const int k0 = ks * 1024 + kt * 64;
        __syncthreads();
#pragma unroll
        for (int mm = 0; mm < 4; ++mm) {
            int d = mm * 32 + sd;
            uint4 v = *(const uint4*)(Htb + (size_t)d * N_NODES + k0 + sc * 8);
            *(uint4*)&htl[d * 64 + ((sc + d) & 7) * 8] = v;
        }
        f32x4 ps0 = zero, ps1 = zero;
#pragma unroll
        for (int h = 0; h < 4; ++h) {
            const bf16x8 kf = *(const bf16x8*)(Kb + ((size_t)h * N_NODES + k0 + w * 16 + lq) * NC + g * 8);
            f32x4 st0 = __builtin_amdgcn_mfma_f32_16x16x32_bf16(kf, qreg0[h], zero, 0, 0, 0);
            f32x4 st1 = __builtin_amdgcn_mfma_f32_16x16x32_bf16(kf, qreg1[h], zero, 0, 0, 0);
#pragma unroll
            for (int r = 0; r < 4; ++r) {
                ps0[r] += fexp2(st0[r] + lg0[h]);
                ps1[r] += fexp2(st1[r] + lg1[h]);
            }
        }
        uint2 pk;
        pk.x = pk2bf(ps0[0], ps0[1]); pk.y = pk2bf(ps0[2], ps0[3]);
        {
            int row = lq;
            *(uint2*)((char*)plds + row * 128 + ((wch + row) & 7) * 16 + whalf) = pk;
        }
        pk.x = pk2bf(ps1[0], ps1[1]); pk.y = pk2bf(ps1[2], ps1[3]);
        {
            int row = 16 + lq;
            *(uint2*)((char*)plds + row * 128 + ((wch + row) & 7) * 16 + whalf) = pk;
        }
        __syncthreads();
#pragma unroll
        for (int kc = 0; kc < 2; ++kc) {
            int row0 = lq, row1 = 16 + lq;
            const bf16x8 af0 = *(const bf16x8*)((char*)plds + row0 * 128 + ((kc * 4 + g + row0) & 7) * 16);
            const bf16x8 af1 = *(const bf16x8*)((char*)plds + row1 * 128 + ((kc * 4 + g + row1) & 7) * 16);
#pragma unroll
            for (int dl = 0; dl < 2; ++dl) {
                int dd = (w * 2 + dl) * 16 + lq;
                const bf16x8 bf = *(const bf16x8*)&htl[dd * 64 + ((kc * 4 + g + dd) & 7) * 8];
                acc[dl][0] = __builtin_amdgcn_mfma_f32_16x16x32_bf16(af0, bf, acc[dl][0], 0, 0, 0);
                acc[dl][1] = __builtin_amdgcn_mfma_f32_16x16x32_bf16(af1, bf, acc[dl][1], 0, 0, 0);
            }
        }
    }
    const size_t ob = (size_t)ks * N_NODES + q0;
#pragma unroll
    for (int dl = 0; dl < 2; ++dl) {
        int d = (w * 2 + dl) * 16 + lq;
#pragma unroll
        for (int s = 0; s < 2; ++s)
#pragma unroll
            for (int r = 0; r < 4; ++r)
                Opart[(ob + s * 16 + 4 * g + r) * DD + d] = acc[dl][s][r];
    }
}

// ===== combine 8 splits, residual, LayerNorm =====
__global__ __launch_bounds__(128) void k_finalize(const float* __restrict__ Opart,
                                                  const float* __restrict__ hb,
                                                  const float* __restrict__ g,
                                                  const float* __restrict__ b,
                                                  float* __restrict__ out) {
    __shared__ float red[2];
    int n = blockIdx.x, c = threadIdx.x;
    const size_t ND = (size_t)N_NODES * DD;
    size_t idx = (size_t)n * DD + c;
    float y = hb[idx];
#pragma unroll
    for (int i = 0; i < 8; ++i) y += Opart[i * ND + idx];
    float s = y;
#pragma unroll
    for (int off = 1; off < 64; off <<= 1) s += __shfl_xor(s, off);
    if ((c & 63) == 0) red[c >> 6] = s;
    __syncthreads();
    float mu = (red[0] + red[1]) * (1.f / 128.f);
    float dv = y - mu;
    float vs = dv * dv;
#pragma unroll
    for (int off = 1; off < 64; off <<= 1) vs += __shfl_xor(vs, off);
    __syncthreads();
    if ((c & 63) == 0) red[c >> 6] = vs;
    __syncthreads();
    float rstd = rsqrtf((red[0] + red[1]) * (1.f / 128.f) + LN_EPS);
    out[idx] = dv * rstd * g[c] + b[c];
}

extern "C" void kernel_launch(void* const* d_in, const int* in_sizes, int n_in,
                              void* d_out, int out_size, void* d_ws, size_t ws_size,
                              hipStream_t stream) {
    const float* x        = (const float*)d_in[0];
    const int*   adj      = (const int*)d_in[1];
    const float* Wgat     = (const float*)d_in[2];
    const float* att_src  = (const float*)d_in[3];
    const float* att_dst  = (const float*)d_in[4];
    const float* bias_gat = (const float*)d_in[5];
    const float* Wq       = (const float*)d_in[6];
    const float* Wk       = (const float*)d_in[7];
    const float* Wpro     = (const float*)d_in[8];
    const float* ln_g     = (const float*)d_in[9];
    const float* ln_b     = (const float*)d_in[10];
    float* out = (float*)d_out;

    const size_t ND = (size_t)N_NODES * DD;
    unsigned short* Qb  = (unsigned short*)d_ws;          // 2 MB
    unsigned short* Kb  = Qb + (1 << 20);                 // 2 MB
    unsigned short* Htb = Kb + (1 << 20);                 // 2 MB
    unsigned short* Wgt = Htb + (1 << 20);                // 64 KB
    unsigned short* Wpt = Wgt + 32768;                    // 32 KB
    unsigned short* Wqt = Wpt + 16384;                    // 32 KB
    unsigned short* Wkt = Wqt + 16384;                    // 32 KB
    float* xw      = (float*)(Wkt + 16384);               // 4 MB
    float* hcat    = xw + ND;                             // 4 MB
    float* hbuf    = hcat + ND;                           // 4 MB
    float* asrc    = hbuf + ND;
    float* adst    = asrc + N_NODES * NH;
    float* nodesum = adst + N_NODES * NH;                 // memset w/ lsum
    float* lsum    = nodesum + N_NODES * NH;
    int*   deg     = (int*)(lsum + N_NODES * NH);
    int*   rowptr  = deg + 8192;
    int*   cursor  = rowptr + 8704;
    int*   src_csr = cursor + 8704;                       // ETOT ints
    float* p_csr   = (float*)(src_csr + ETOT);            // ETOT*4 floats
    float* Opart   = p_csr + (size_t)ETOT * 4;            // 8 x [N,128] = 32 MB

    hipMemsetAsync(nodesum, 0, 2 * N_NODES * NH * sizeof(float), stream);
    hipMemsetAsync(deg, 0, N_NODES * sizeof(int), stream);
    k_cvt<<<320, 256, 0, stream>>>(Wgat, Wpro, Wq, Wk, Wgt, Wpt, Wqt, Wkt);
    k_gemm_att<<<N_NODES / 32, 256, 0, stream>>>(x, Wgt, att_src, att_dst, xw, asrc, adst);
    int eblocks = (ETOT + 255) / 256;
    k_deg<<<eblocks, 256, 0, stream>>>(adj, deg);
    k_scan<<<1, 1024, 0, stream>>>(deg, rowptr, cursor);
    k_fill<<<eblocks, 256, 0, stream>>>(adj, asrc, adst, cursor, src_csr, p_csr, nodesum);
    k_aggregate<<<N_NODES / 2, 256, 0, stream>>>(rowptr, src_csr, p_csr, nodesum, xw, bias_gat, hcat);
    k_gemm_pro<<<N_NODES / 32, 256, 0, stream>>>(hcat, Wpt, Wqt, Wkt, hbuf, Htb, Qb, Kb);
    dim3 lgrid(N_NODES / 64, 8);
    k_attn_l<<<lgrid, 256, 0, stream>>>(Qb, Kb, lsum);
    dim3 agrid(N_NODES / 32, 8);
    k_attn_pv<<<agrid, 256, 0, stream>>>(Qb, Kb, Htb, lsum, Opart);
    k_finalize<<<N_NODES, 128, 0, stream>>>(Opart, hbuf, ln_g, ln_b, out);
}

// Round 13
// 265.981 us; speedup vs baseline: 1.4878x; 1.2006x over previous
//
#include <hip/hip_runtime.h>
#include <math.h>

#define N_NODES 8192
#define E_EDGES 262144
#define ETOT (E_EDGES + N_NODES)
#define F_IN 256
#define NH 4
#define NC 32
#define DD 128
#define NEG_SLOPE 0.2f
#define LN_EPS 1e-5f
// attention softmax in exp2 domain: fold log2(e)/sqrt(32) into Q at pack time
#define QK_SCALE (1.4426950408889634f / 5.656854249492381f)

typedef __attribute__((ext_vector_type(8))) short bf16x8;
typedef __attribute__((ext_vector_type(4))) float f32x4;

__device__ __forceinline__ float fexp2(float x) { return __builtin_amdgcn_exp2f(x); }
__device__ __forceinline__ float flog2(float x) { return __builtin_amdgcn_logf(x); }
__device__ __forceinline__ float frcp(float x)  { return __builtin_amdgcn_rcpf(x); }

__device__ __forceinline__ unsigned short f2bf(float f) {   // RTNE
    unsigned u = __float_as_uint(f);
    u += 0x7FFFu + ((u >> 16) & 1u);
    return (unsigned short)(u >> 16);
}
__device__ __forceinline__ unsigned pk2bf(float lo, float hi) {
    unsigned a = __float_as_uint(lo) + 0x8000u;
    unsigned b = __float_as_uint(hi) + 0x8000u;
    return __builtin_amdgcn_perm(b, a, 0x07060302u);
}

// ===== combined weight transpose/convert to bf16 =====
__global__ __launch_bounds__(256) void k_cvt(const float* __restrict__ Wgat,
                                             const float* __restrict__ Wpro,
                                             const float* __restrict__ Wq,
                                             const float* __restrict__ Wk,
                                             unsigned short* __restrict__ Wgt,
                                             unsigned short* __restrict__ Wpt,
                                             unsigned short* __restrict__ Wqt,
                                             unsigned short* __restrict__ Wkt) {
    int t = blockIdx.x * 256 + threadIdx.x;   // 81920 total
    if (t < 32768) {
        int c = t >> 8, k = t & 255;
        Wgt[t] = f2bf(Wgat[(size_t)k * 128 + c]);
    } else if (t < 49152) {
        int i = t - 32768, c = i >> 7, k = i & 127;
        Wpt[i] = f2bf(Wpro[(size_t)k * 128 + c]);
    } else if (t < 65536) {
        int i = t - 49152, h = i >> 12, r = i & 4095, c = r >> 7, k = r & 127;
        Wqt[i] = f2bf(Wq[h * 4096 + k * 32 + c]);
    } else if (t < 81920) {
        int i = t - 65536, h = i >> 12, r = i & 4095, c = r >> 7, k = r & 127;
        Wkt[i] = f2bf(Wk[h * 4096 + k * 32 + c]);
    }
}

// ===== MFMA GEMM xw = x @ Wgat, x converted to bf16 in staging, fused attcoef =====
__global__ __launch_bounds__(256) void k_gemm_att(const float* __restrict__ x,
                                                  const unsigned short* __restrict__ Wgt,
                                                  const float* __restrict__ att_src,
                                                  const float* __restrict__ att_dst,
                                                  float* __restrict__ xw,
                                                  float* __restrict__ asrc,
                                                  float* __restrict__ adst) {
    __shared__ unsigned short xs[32 * 256];   // chunk-rotated
    const int tid = threadIdx.x;
    const int w = tid >> 6, lane = tid & 63, lq = lane & 15, g = lane >> 4;
    const int n0 = blockIdx.x * 32;
#pragma unroll
    for (int m = 0; m < 4; ++m) {             // 1024 chunk-tasks
        int lin = m * 256 + tid;
        int row = lin >> 5, ch = lin & 31;
        const float* src = &x[(size_t)(n0 + row) * 256 + ch * 8];
        float4 v0 = *(const float4*)src;
        float4 v1 = *(const float4*)(src + 4);
        uint4 o;
        o.x = (unsigned)f2bf(v0.x) | ((unsigned)f2bf(v0.y) << 16);
        o.y = (unsigned)f2bf(v0.z) | ((unsigned)f2bf(v0.w) << 16);
        o.z = (unsigned)f2bf(v1.x) | ((unsigned)f2bf(v1.y) << 16);
        o.w = (unsigned)f2bf(v1.z) | ((unsigned)f2bf(v1.w) << 16);
        *(uint4*)&xs[row * 256 + ((ch + row) & 31) * 8] = o;
    }
    __syncthreads();
    f32x4 zero = {0.f, 0.f, 0.f, 0.f};
    f32x4 acc[2][2];
#pragma unroll
    for (int s = 0; s < 2; ++s) { acc[s][0] = zero; acc[s][1] = zero; }
#pragma unroll
    for (int kb = 0; kb < 8; ++kb) {
        bf16x8 af[2], bf[2];
#pragma unroll
        for (int s = 0; s < 2; ++s) {
            int row = s * 16 + lq;
            af[s] = *(const bf16x8*)&xs[row * 256 + (((kb * 4 + g) + row) & 31) * 8];
        }
#pragma unroll
        for (int c = 0; c < 2; ++c)
            bf[c] = *(const bf16x8*)(Wgt + (size_t)(w * 32 + c * 16 + lq) * 256 + kb * 32 + g * 8);
#pragma unroll
        for (int s = 0; s < 2; ++s)
#pragma unroll
            for (int c = 0; c < 2; ++c)
                acc[s][c] = __builtin_amdgcn_mfma_f32_16x16x32_bf16(af[s], bf[c], acc[s][c], 0, 0, 0);
    }
#pragma unroll
    for (int s = 0; s < 2; ++s)
#pragma unroll
        for (int c = 0; c < 2; ++c)
#pragma unroll
            for (int r = 0; r < 4; ++r)
                xw[(size_t)(n0 + s * 16 + 4 * g + r) * DD + w * 32 + c * 16 + lq] = acc[s][c][r];
    float avs0 = att_src[w * 32 + lq],      avd0 = att_dst[w * 32 + lq];
    float avs1 = att_src[w * 32 + 16 + lq], avd1 = att_dst[w * 32 + 16 + lq];
#pragma unroll
    for (int s = 0; s < 2; ++s) {
        f32x4 vs, vd;
#pragma unroll
        for (int r = 0; r < 4; ++r) {
            vs[r] = acc[s][0][r] * avs0 + acc[s][1][r] * avs1;
            vd[r] = acc[s][0][r] * avd0 + acc[s][1][r] * avd1;
        }
#pragma unroll
        for (int off = 1; off < 16; off <<= 1)
#pragma unroll
            for (int r = 0; r < 4; ++r) {
                vs[r] += __shfl_xor(vs[r], off);
                vd[r] += __shfl_xor(vd[r], off);
            }
        if (lq == 0) {
#pragma unroll
            for (int r = 0; r < 4; ++r) {
                asrc[(n0 + s * 16 + 4 * g + r) * 4 + w] = vs[r];
                adst[(n0 + s * 16 + 4 * g + r) * 4 + w] = vd[r];
            }
        }
    }
}

// ===== MFMA GEMM h = hcat @ Wpro + hbuf f32 + Htb transpose + MFMA q/k =====
__global__ __launch_bounds__(256) void k_gemm_pro(const float* __restrict__ hcat,
                                                  const unsigned short* __restrict__ Wpt,
                                                  const unsigned short* __restrict__ Wqt,
                                                  const unsigned short* __restrict__ Wkt,
                                                  float* __restrict__ hbuf,
                                                  unsigned short* __restrict__ Htb,
                                                  unsigned short* __restrict__ Qb,
                                                  unsigned short* __restrict__ Kb) {
    __shared__ unsigned short xs[32 * 128];
    __shared__ unsigned short hsd[32 * 128];
    const int tid = threadIdx.x;
    const int w = tid >> 6, lane = tid & 63, lq = lane & 15, g = lane >> 4;
    const int n0 = blockIdx.x * 32;
#pragma unroll
    for (int m = 0; m < 2; ++m) {
        int lin = m * 256 + tid;
        int row = lin >> 4, ch = lin & 15;
        const float* src = &hcat[(size_t)(n0 + row) * 128 + ch * 8];
        float4 v0 = *(const float4*)src;
        float4 v1 = *(const float4*)(src + 4);
        uint4 o;
        o.x = (unsigned)f2bf(v0.x) | ((unsigned)f2bf(v0.y) << 16);
        o.y = (unsigned)f2bf(v0.z) | ((unsigned)f2bf(v0.w) << 16);
        o.z = (unsigned)f2bf(v1.x) | ((unsigned)f2bf(v1.y) << 16);
        o.w = (unsigned)f2bf(v1.z) | ((unsigned)f2bf(v1.w) << 16);
        *(uint4*)&xs[row * 128 + ((ch + row) & 15) * 8] = o;
    }
    __syncthreads();
    f32x4 zero = {0.f, 0.f, 0.f, 0.f};
    f32x4 acc[2][2];
#pragma unroll
    for (int s = 0; s < 2; ++s) { acc[s][0] = zero; acc[s][1] = zero; }
#pragma unroll
    for (int kb = 0; kb < 4; ++kb) {
        bf16x8 af[2], bf[2];
#pragma unroll
        for (int s = 0; s < 2; ++s) {
            int row = s * 16 + lq;
            af[s] = *(const bf16x8*)&xs[row * 128 + (((kb * 4 + g) + row) & 15) * 8];
        }
#pragma unroll
        for (int c = 0; c < 2; ++c)
            bf[c] = *(const bf16x8*)(Wpt + (size_t)(w * 32 + c * 16 + lq) * 128 + kb * 32 + g * 8);
#pragma unroll
        for (int s = 0; s < 2; ++s)
#pragma unroll
            for (int c = 0; c < 2; ++c)
                acc[s][c] = __builtin_amdgcn_mfma_f32_16x16x32_bf16(af[s], bf[c], acc[s][c], 0, 0, 0);
    }
#pragma unroll
    for (int s = 0; s < 2; ++s)
#pragma unroll
        for (int c = 0; c < 2; ++c) {
            int col = w * 32 + c * 16 + lq;
#pragma unroll
            for (int r = 0; r < 4; ++r) {
                int row = s * 16 + 4 * g + r;
                hbuf[(size_t)(n0 + row) * 128 + col] = acc[s][c][r];
                hsd[row * 128 + (((col >> 3) + row) & 15) * 8 + (col & 7)] = f2bf(acc[s][c][r]);
            }
            uint2 hp;
            hp.x = pk2bf(acc[s][c][0], acc[s][c][1]);
            hp.y = pk2bf(acc[s][c][2], acc[s][c][3]);
            *(uint2*)(Htb + (size_t)col * N_NODES + n0 + s * 16 + 4 * g) = hp;
        }
    __syncthreads();
    f32x4 aq[2][2], ak[2][2];
#pragma unroll
    for (int s = 0; s < 2; ++s)
#pragma unroll
        for (int c = 0; c < 2; ++c) { aq[s][c] = zero; ak[s][c] = zero; }
#pragma unroll
    for (int kb = 0; kb < 4; ++kb) {
        bf16x8 af[2], bq[2], bk[2];
#pragma unroll
        for (int s = 0; s < 2; ++s) {
            int row = s * 16 + lq;
            af[s] = *(const bf16x8*)&hsd[row * 128 + (((kb * 4 + g) + row) & 15) * 8];
        }
#pragma unroll
        for (int c = 0; c < 2; ++c) {
            size_t widx = ((size_t)w * 32 + c * 16 + lq) * 128 + kb * 32 + g * 8;
            bq[c] = *(const bf16x8*)(Wqt + widx);
            bk[c] = *(const bf16x8*)(Wkt + widx);
        }
#pragma unroll
        for (int s = 0; s < 2; ++s)
#pragma unroll
            for (int c = 0; c < 2; ++c) {
                aq[s][c] = __builtin_amdgcn_mfma_f32_16x16x32_bf16(af[s], bq[c], aq[s][c], 0, 0, 0);
                ak[s][c] = __builtin_amdgcn_mfma_f32_16x16x32_bf16(af[s], bk[c], ak[s][c], 0, 0, 0);
            }
    }
#pragma unroll
    for (int s = 0; s < 2; ++s)
#pragma unroll
        for (int c = 0; c < 2; ++c)
#pragma unroll
            for (int r = 0; r < 4; ++r) {
                size_t nidx = (size_t)w * N_NODES + n0 + s * 16 + 4 * g + r;
                Qb[nidx * NC + c * 16 + lq] = f2bf(aq[s][c][r] * QK_SCALE);
                Kb[nidx * NC + c * 16 + lq] = f2bf(ak[s][c][r]);
            }
}

__device__ __forceinline__ void edge_sd(int e, const int* adj, int& s, int& d) {
    if (e < E_EDGES) { s = adj[e]; d = adj[E_EDGES + e]; }
    else { s = e - E_EDGES; d = s; }
}

// ===== degree count only =====
__global__ void k_deg(const int* __restrict__ adj, int* __restrict__ deg) {
    int e = blockIdx.x * blockDim.x + threadIdx.x;
    if (e >= ETOT) return;
    int d = (e < E_EDGES) ? adj[E_EDGES + e] : e - E_EDGES;
    atomicAdd(&deg[d], 1);
}

// ===== single-block exclusive scan over deg[8192] -> rowptr, cursor =====
__global__ __launch_bounds__(1024) void k_scan(const int* __restrict__ deg,
                                               int* __restrict__ rowptr,
                                               int* __restrict__ cursor) {
    __shared__ int sm[1024];
    int t = threadIdx.x;
    int v[8], sum = 0;
#pragma unroll
    for (int j = 0; j < 8; ++j) { v[j] = deg[t * 8 + j]; sum += v[j]; }
    sm[t] = sum;
    __syncthreads();
    for (int off = 1; off < 1024; off <<= 1) {
        int x = (t >= off) ? sm[t - off] : 0;
        __syncthreads();
        sm[t] += x;
        __syncthreads();
    }
    int base = sm[t] - sum;
#pragma unroll
    for (int j = 0; j < 8; ++j) {
        rowptr[t * 8 + j] = base;
        cursor[t * 8 + j] = base;
        base += v[j];
    }
    if (t == 1023) rowptr[8192] = base;
}

// ===== fill CSR: ONE packed 16B record per edge {src, p01 bf16, p23 bf16, 0} =====
__global__ void k_fill(const int* __restrict__ adj, const float* __restrict__ asrc,
                       const float* __restrict__ adst, int* __restrict__ cursor,
                       uint4* __restrict__ rec_csr) {
    int e = blockIdx.x * blockDim.x + threadIdx.x;
    if (e >= ETOT) return;
    int s, d; edge_sd(e, adj, s, d);
    int pos = atomicAdd(&cursor[d], 1);
    float4 as4 = *(const float4*)&asrc[s * 4];
    float4 ad4 = *(const float4*)&adst[d * 4];
    const float L2E = 1.4426950408889634f;
    float v;
    float4 p;
    v = as4.x + ad4.x; v = v > 0.f ? v : NEG_SLOPE * v; p.x = fexp2(v * L2E);
    v = as4.y + ad4.y; v = v > 0.f ? v : NEG_SLOPE * v; p.y = fexp2(v * L2E);
    v = as4.z + ad4.z; v = v > 0.f ? v : NEG_SLOPE * v; p.z = fexp2(v * L2E);
    v = as4.w + ad4.w; v = v > 0.f ? v : NEG_SLOPE * v; p.w = fexp2(v * L2E);
    uint4 rec;
    rec.x = (unsigned)s;
    rec.y = pk2bf(p.x, p.y);
    rec.z = pk2bf(p.z, p.w);
    rec.w = 0u;
    rec_csr[pos] = rec;
}

// ===== per-node gather-aggregate: inline denominator, no nodesum array =====
__global__ __launch_bounds__(256) void k_aggregate(const int* __restrict__ rowptr,
                                                   const uint4* __restrict__ rec_csr,
                                                   const float* __restrict__ xw,
                                                   const float* __restrict__ bias,
                                                   float* __restrict__ hcat) {
    int n = blockIdx.x * 2 + (threadIdx.x >> 7);
    int c = threadIdx.x & 127;
    int h = c >> 5;
    int beg = rowptr[n], end = rowptr[n + 1];
    float acc = 0.f, den = 0.f;
    int i = beg;
    for (; i + 2 <= end; i += 2) {
        uint4 r0 = rec_csr[i], r1 = rec_csr[i + 1];
        unsigned w0 = (h < 2) ? r0.y : r0.z;
        unsigned w1 = (h < 2) ? r1.y : r1.z;
        float p0 = __uint_as_float((h & 1) ? (w0 & 0xFFFF0000u) : (w0 << 16));
        float p1 = __uint_as_float((h & 1) ? (w1 & 0xFFFF0000u) : (w1 << 16));
        den += p0 + p1;
        acc += p0 * xw[(size_t)r0.x * DD + c] + p1 * xw[(size_t)r1.x * DD + c];
    }
    if (i < end) {
        uint4 r0 = rec_csr[i];
        unsigned w0 = (h < 2) ? r0.y : r0.z;
        float p0 = __uint_as_float((h & 1) ? (w0 & 0xFFFF0000u) : (w0 << 16));
        den += p0;
        acc += p0 * xw[(size_t)r0.x * DD + c];
    }
    hcat[(size_t)n * DD + c] = bias[c] + acc * frcp(den);
}

// ===== attention pass A: l_h[n] = sum_m exp2(S) — 64q/block, ksplit 8 =====
__global__ __launch_bounds__(256) void k_attn_l(const unsigned short* __restrict__ Qb,
                                                const unsigned short* __restrict__ Kb,
                                                float* __restrict__ lsum) {
    const int tid = threadIdx.x;
    const int w = tid >> 6;
    const int lane = tid & 63;
    const int lq = lane & 15;
    const int g = lane >> 4;
    const int q0 = blockIdx.x * 64;
    const int ks = blockIdx.y;
    f32x4 zero = {0.f, 0.f, 0.f, 0.f};

    bf16x8 qf[4];
#pragma unroll
    for (int j = 0; j < 4; ++j)
        qf[j] = *(const bf16x8*)(Qb + ((size_t)w * N_NODES + q0 + j * 16 + lq) * NC + g * 8);
    const unsigned short* Kp = Kb + (size_t)w * N_NODES * NC;

    float l[4] = {0.f, 0.f, 0.f, 0.f};
    for (int kt = 0; kt < 16; ++kt) {
        const int k0 = ks * 1024 + kt * 64;
#pragma unroll
        for (int t = 0; t < 4; ++t) {
            const bf16x8 kf = *(const bf16x8*)(Kp + (size_t)(k0 + t * 16 + lq) * NC + g * 8);
#pragma unroll
            for (int j = 0; j < 4; ++j) {
                f32x4 st = __builtin_amdgcn_mfma_f32_16x16x32_bf16(kf, qf[j], zero, 0, 0, 0);
                l[j] += (fexp2(st[0]) + fexp2(st[1])) + (fexp2(st[2]) + fexp2(st[3]));
            }
        }
    }
#pragma unroll
    for (int j = 0; j < 4; ++j) {
        float lj = l[j];
        lj += __shfl_xor(lj, 16); lj += __shfl_xor(lj, 32);
        if (lane < 16) atomicAdd(&lsum[w * N_NODES + q0 + j * 16 + lq], lj);
    }
}

// ===== attention pass B: head-merged PV, 32q/block, ksplit 8, 20480B LDS =====
__global__ __launch_bounds__(256, 2) void k_attn_pv(
        const unsigned short* __restrict__ Qb,
        const unsigned short* __restrict__ Kb,
        const unsigned short* __restrict__ Htb,
        const float* __restrict__ lsum,
        float* __restrict__ Opart) {
    __shared__ unsigned short htl[128 * 64];    // 16384 B, chunk-rotated
    __shared__ unsigned short plds[32 * 64];    // 4096 B, chunk-rotated
    const int tid = threadIdx.x;
    const int w = tid >> 6;
    const int lane = tid & 63;
    const int lq = lane & 15;
    const int g = lane >> 4;
    const int q0 = blockIdx.x * 32;
    const int ks = blockIdx.y;
    const int sd = tid >> 3, sc = tid & 7;
    f32x4 zero = {0.f, 0.f, 0.f, 0.f};

    float lg0[4], lg1[4];
    bf16x8 qreg0[4], qreg1[4];
#pragma unroll
    for (int h = 0; h < 4; ++h) {
        lg0[h] = -flog2(lsum[h * N_NODES + q0 + lq]);
        lg1[h] = -flog2(lsum[h * N_NODES + q0 + 16 + lq]);
        qreg0[h] = *(const bf16x8*)(Qb + ((size_t)h * N_NODES + q0 + lq) * NC + g * 8);
        qreg1[h] = *(const bf16x8*)(Qb + ((size_t)h * N_NODES + q0 + 16 + lq) * NC + g * 8);
    }

    f32x4 acc[2][2];
#pragma unroll
    for (int a = 0; a < 2; ++a) { acc[a][0] = zero; acc[a][1] = zero; }

    const int wch = 2 * w + (g >> 1);
    const int whalf = (g & 1) * 8;

    for (int kt = 0; kt < 16; ++kt) {
        const int k0 = ks * 1024 + kt * 64;
        __syncthreads();
#pragma unroll
        for (int mm = 0; mm < 4; ++mm) {
            int d = mm * 32 + sd;
            uint4 v = *(const uint4*)(Htb + (size_t)d * N_NODES + k0 + sc * 8);
            *(uint4*)&htl[d * 64 + ((sc + d) & 7) * 8] = v;
        }
        f32x4 ps0 = zero, ps1 = zero;
#pragma unroll
        for (int h = 0; h < 4; ++h) {
            const bf16x8 kf = *(const bf16x8*)(Kb + ((size_t)h * N_NODES + k0 + w * 16 + lq) * NC + g * 8);
            f32x4 st0 = __builtin_amdgcn_mfma_f32_16x16x32_bf16(kf, qreg0[h], zero, 0, 0, 0);
            f32x4 st1 = __builtin_amdgcn_mfma_f32_16x16x32_bf16(kf, qreg1[h], zero, 0, 0, 0);
#pragma unroll
            for (int r = 0; r < 4; ++r) {
                ps0[r] += fexp2(st0[r] + lg0[h]);
                ps1[r] += fexp2(st1[r] + lg1[h]);
            }
        }
        uint2 pk;
        pk.x = pk2bf(ps0[0], ps0[1]); pk.y = pk2bf(ps0[2], ps0[3]);
        {
            int row = lq;
            *(uint2*)((char*)plds + row * 128 + ((wch + row) & 7) * 16 + whalf) = pk;
        }
        pk.x = pk2bf(ps1[0], ps1[1]); pk.y = pk2bf(ps1[2], ps1[3]);
        {
            int row = 16 + lq;
            *(uint2*)((char*)plds + row * 128 + ((wch + row) & 7) * 16 + whalf) = pk;
        }
        __syncthreads();
#pragma unroll
        for (int kc = 0; kc < 2; ++kc) {
            int row0 = lq, row1 = 16 + lq;
            const bf16x8 af0 = *(const bf16x8*)((char*)plds + row0 * 128 + ((kc * 4 + g + row0) & 7) * 16);
            const bf16x8 af1 = *(const bf16x8*)((char*)plds + row1 * 128 + ((kc * 4 + g + row1) & 7) * 16);
#pragma unroll
            for (int dl = 0; dl < 2; ++dl) {
                int dd = (w * 2 + dl) * 16 + lq;
                const bf16x8 bf = *(const bf16x8*)&htl[dd * 64 + ((kc * 4 + g + dd) & 7) * 8];
                acc[dl][0] = __builtin_amdgcn_mfma_f32_16x16x32_bf16(af0, bf, acc[dl][0], 0, 0, 0);
                acc[dl][1] = __builtin_amdgcn_mfma_f32_16x16x32_bf16(af1, bf, acc[dl][1], 0, 0, 0);
            }
        }
    }
    const size_t ob = (size_t)ks * N_NODES + q0;
#pragma unroll
    for (int dl = 0; dl < 2; ++dl) {
        int d = (w * 2 + dl) * 16 + lq;
#pragma unroll
        for (int s = 0; s < 2; ++s)
#pragma unroll
            for (int r = 0; r < 4; ++r)
                Opart[(ob + s * 16 + 4 * g + r) * DD + d] = acc[dl][s][r];
    }
}

// ===== combine 8 splits, residual, LayerNorm =====
__global__ __launch_bounds__(128) void k_finalize(const float* __restrict__ Opart,
                                                  const float* __restrict__ hb,
                                                  const float* __restrict__ g,
                                                  const float* __restrict__ b,
                                                  float* __restrict__ out) {
    __shared__ float red[2];
    int n = blockIdx.x, c = threadIdx.x;
    const size_t ND = (size_t)N_NODES * DD;
    size_t idx = (size_t)n * DD + c;
    float y = hb[idx];
#pragma unroll
    for (int i = 0; i < 8; ++i) y += Opart[i * ND + idx];
    float s = y;
#pragma unroll
    for (int off = 1; off < 64; off <<= 1) s += __shfl_xor(s, off);
    if ((c & 63) == 0) red[c >> 6] = s;
    __syncthreads();
    float mu = (red[0] + red[1]) * (1.f / 128.f);
    float dv = y - mu;
    float vs = dv * dv;
#pragma unroll
    for (int off = 1; off < 64; off <<= 1) vs += __shfl_xor(vs, off);
    __syncthreads();
    if ((c & 63) == 0) red[c >> 6] = vs;
    __syncthreads();
    float rstd = rsqrtf((red[0] + red[1]) * (1.f / 128.f) + LN_EPS);
    out[idx] = dv * rstd * g[c] + b[c];
}

extern "C" void kernel_launch(void* const* d_in, const int* in_sizes, int n_in,
                              void* d_out, int out_size, void* d_ws, size_t ws_size,
                              hipStream_t stream) {
    const float* x        = (const float*)d_in[0];
    const int*   adj      = (const int*)d_in[1];
    const float* Wgat     = (const float*)d_in[2];
    const float* att_src  = (const float*)d_in[3];
    const float* att_dst  = (const float*)d_in[4];
    const float* bias_gat = (const float*)d_in[5];
    const float* Wq       = (const float*)d_in[6];
    const float* Wk       = (const float*)d_in[7];
    const float* Wpro     = (const float*)d_in[8];
    const float* ln_g     = (const float*)d_in[9];
    const float* ln_b     = (const float*)d_in[10];
    float* out = (float*)d_out;

    const size_t ND = (size_t)N_NODES * DD;
    unsigned short* Qb  = (unsigned short*)d_ws;          // 2 MB
    unsigned short* Kb  = Qb + (1 << 20);                 // 2 MB
    unsigned short* Htb = Kb + (1 << 20);                 // 2 MB
    unsigned short* Wgt = Htb + (1 << 20);                // 64 KB
    unsigned short* Wpt = Wgt + 32768;                    // 32 KB
    unsigned short* Wqt = Wpt + 16384;                    // 32 KB
    unsigned short* Wkt = Wqt + 16384;                    // 32 KB
    float* xw      = (float*)(Wkt + 16384);               // 4 MB
    float* hcat    = xw + ND;                             // 4 MB
    float* hbuf    = hcat + ND;                           // 4 MB
    float* asrc    = hbuf + ND;
    float* adst    = asrc + N_NODES * NH;
    float* lsum    = adst + N_NODES * NH;                 // 128 KB (memset w/ deg)
    int*   deg     = (int*)(lsum + N_NODES * NH);         // 32 KB
    int*   rowptr  = deg + 8192;
    int*   cursor  = rowptr + 8704;
    uint4* rec_csr = (uint4*)(cursor + 8704);             // ETOT*16B = 4.3 MB
    float* Opart   = (float*)(rec_csr + ETOT);            // 8 x [N,128] = 32 MB

    hipMemsetAsync(lsum, 0, N_NODES * NH * sizeof(float) + N_NODES * sizeof(int), stream);
    k_cvt<<<320, 256, 0, stream>>>(Wgat, Wpro, Wq, Wk, Wgt, Wpt, Wqt, Wkt);
    k_gemm_att<<<N_NODES / 32, 256, 0, stream>>>(x, Wgt, att_src, att_dst, xw, asrc, adst);
    int eblocks = (ETOT + 255) / 256;
    k_deg<<<eblocks, 256, 0, stream>>>(adj, deg);
    k_scan<<<1, 1024, 0, stream>>>(deg, rowptr, cursor);
    k_fill<<<eblocks, 256, 0, stream>>>(adj, asrc, adst, cursor, rec_csr);
    k_aggregate<<<N_NODES / 2, 256, 0, stream>>>(rowptr, rec_csr, xw, bias_gat, hcat);
    k_gemm_pro<<<N_NODES / 32, 256, 0, stream>>>(hcat, Wpt, Wqt, Wkt, hbuf, Htb, Qb, Kb);
    dim3 lgrid(N_NODES / 64, 8);
    k_attn_l<<<lgrid, 256, 0, stream>>>(Qb, Kb, lsum);
    dim3 agrid(N_NODES / 32, 8);
    k_attn_pv<<<agrid, 256, 0, stream>>>(Qb, Kb, Htb, lsum, Opart);
    k_finalize<<<N_NODES, 128, 0, stream>>>(Opart, hbuf, ln_g, ln_b, out);
}